// Round 1
// baseline (7683.018 us; speedup 1.0000x reference)
//
#include <hip/hip_runtime.h>
#include <hip/hip_bf16.h>
#include <math.h>

#define TOK 8192   // B*L
#define DM 512
#define NH 8
#define DKH 64
#define DFFN 2048
#define SEQ 1024
#define NBLK 4
#define NUMC 1000

// ---------------------------------------------------------------- embed
__global__ __launch_bounds__(256) void embed_kernel(
    const int* __restrict__ q, const int* __restrict__ r,
    const float* __restrict__ ctx_emb, const float* __restrict__ val_emb,
    const float* __restrict__ pos_emb,
    float* __restrict__ ctx, float* __restrict__ val)
{
    const int t = blockIdx.x;
    const int inter = q[t] + NUMC * r[t];
    const int l = t & (SEQ - 1);
    const float* ce = ctx_emb + (size_t)inter * DM;
    const float* ve = val_emb + (size_t)inter * DM;
    const float* pe = pos_emb + (size_t)l * DM;
    float* cp = ctx + (size_t)t * DM;
    float* vp = val + (size_t)t * DM;
    for (int d = threadIdx.x; d < DM; d += 256) {
        float p = pe[d];
        cp[d] = ce[d] + p;
        vp[d] = ve[d] + p;
    }
}

// ---------------------------------------------------------------- GEMM
// C[M,N] = A[M,K] @ W[K,N] + bias[N], optional ReLU.
// 128x128 block tile, K-tile 32, 256 threads, 8x8 micro-tile
// (split as rows {ty*4..+3, 64+ty*4..+3} x cols {tx*4..+3, 64+tx*4..+3}).
__global__ __launch_bounds__(256) void gemm_kernel(
    const float* __restrict__ A, const float* __restrict__ W,
    const float* __restrict__ bias, float* __restrict__ C,
    int M, int N, int K, int relu)
{
    __shared__ float As[32][128];   // transposed: As[k][m]
    __shared__ float Bs[32][128];   // Bs[k][n]
    const int tid = threadIdx.x;
    const int tx = tid & 15;
    const int ty = tid >> 4;
    const int bm = blockIdx.y * 128;
    const int bn = blockIdx.x * 128;
    const int ak  = (tid & 7) * 4;   // k offset within tile for A load
    const int ar  = tid >> 3;        // 0..31 row base for A load
    const int bn4 = (tid & 31) * 4;  // n offset for B load
    const int bk0 = tid >> 5;        // 0..7 k base for B load

    float acc[8][8];
#pragma unroll
    for (int i = 0; i < 8; ++i)
#pragma unroll
        for (int j = 0; j < 8; ++j) acc[i][j] = 0.f;

    for (int k0 = 0; k0 < K; k0 += 32) {
        float4 a[4], b[4];
#pragma unroll
        for (int p = 0; p < 4; ++p)
            a[p] = *(const float4*)(A + (size_t)(bm + ar + p * 32) * K + (k0 + ak));
#pragma unroll
        for (int p = 0; p < 4; ++p)
            b[p] = *(const float4*)(W + (size_t)(k0 + bk0 + p * 8) * N + (bn + bn4));
        __syncthreads();   // previous tile's compute done before overwrite
#pragma unroll
        for (int p = 0; p < 4; ++p) {
            const int rr = ar + p * 32;
            As[ak + 0][rr] = a[p].x;
            As[ak + 1][rr] = a[p].y;
            As[ak + 2][rr] = a[p].z;
            As[ak + 3][rr] = a[p].w;
            *(float4*)&Bs[bk0 + p * 8][bn4] = b[p];
        }
        __syncthreads();
#pragma unroll
        for (int kk = 0; kk < 32; ++kk) {
            const float4 a0 = *(const float4*)&As[kk][ty * 4];
            const float4 a1 = *(const float4*)&As[kk][64 + ty * 4];
            const float4 b0 = *(const float4*)&Bs[kk][tx * 4];
            const float4 b1 = *(const float4*)&Bs[kk][64 + tx * 4];
            const float av[8] = {a0.x, a0.y, a0.z, a0.w, a1.x, a1.y, a1.z, a1.w};
            const float bv[8] = {b0.x, b0.y, b0.z, b0.w, b1.x, b1.y, b1.z, b1.w};
#pragma unroll
            for (int i = 0; i < 8; ++i)
#pragma unroll
                for (int j = 0; j < 8; ++j)
                    acc[i][j] = fmaf(av[i], bv[j], acc[i][j]);
        }
    }

    const float4 bias0 = *(const float4*)(bias + bn + tx * 4);
    const float4 bias1 = *(const float4*)(bias + bn + 64 + tx * 4);
    const float bb[8] = {bias0.x, bias0.y, bias0.z, bias0.w,
                         bias1.x, bias1.y, bias1.z, bias1.w};
#pragma unroll
    for (int i = 0; i < 8; ++i) {
        const int row = bm + ((i < 4) ? (ty * 4 + i) : (64 + ty * 4 + (i - 4)));
        float o[8];
#pragma unroll
        for (int j = 0; j < 8; ++j) {
            o[j] = acc[i][j] + bb[j];
            if (relu) o[j] = fmaxf(o[j], 0.f);
        }
        float4 o0 = {o[0], o[1], o[2], o[3]};
        float4 o1 = {o[4], o[5], o[6], o[7]};
        *(float4*)(C + (size_t)row * N + (bn + tx * 4)) = o0;
        *(float4*)(C + (size_t)row * N + (bn + 64 + tx * 4)) = o1;
    }
}

// ---------------------------------------------------------------- attention
// One block per (b, h, 64-row q-tile). j-tiles of 32 with online softmax.
// Q/K/V/O layout: [b*SEQ + l][h*DKH + d]  (i.e. [TOK][DM]).
__global__ __launch_bounds__(256) void attn_kernel(
    const float* __restrict__ Qg, const float* __restrict__ Kg,
    const float* __restrict__ Vg, float* __restrict__ Og)
{
    __shared__ float Qs[64][65];
    __shared__ float Ks[32][65];
    __shared__ float Vs[32][65];
    __shared__ float Ps[64][33];
    __shared__ float red[64][17];
    __shared__ float mrow[64];
    __shared__ float lrow[64];
    __shared__ float arow[64];

    const int tid = threadIdx.x;
    const int tx = tid & 15;       // j pairs (S) / d columns (PV)
    const int ty = tid >> 4;       // q rows (4 each)
    const int qt = blockIdx.x;
    const int b = blockIdx.y >> 3;
    const int h = blockIdx.y & 7;
    const size_t base = (size_t)b * SEQ * DM + (size_t)h * DKH;

    // Q tile load: 64 rows x 64 cols
    {
        const int rw = tid >> 2;
        const int c0 = (tid & 3) * 16;
        const float* src = Qg + base + (size_t)(qt * 64 + rw) * DM + c0;
#pragma unroll
        for (int j = 0; j < 16; ++j) Qs[rw][c0 + j] = src[j];
    }
    if (tid < 64) { mrow[tid] = -INFINITY; lrow[tid] = 0.f; }

    float oacc[4][4];
#pragma unroll
    for (int i = 0; i < 4; ++i)
#pragma unroll
        for (int j = 0; j < 4; ++j) oacc[i][j] = 0.f;

    const int nkt = 2 * qt + 2;   // causal: j-tiles of 32 up to row qt*64+63
    for (int kt = 0; kt < nkt; ++kt) {
        __syncthreads();   // previous PV / init done before K,V overwrite
        {
            const int rw = tid >> 3;          // 0..31
            const int c0 = (tid & 7) * 8;     // 0..56
            const float* ks = Kg + base + (size_t)(kt * 32 + rw) * DM + c0;
            const float* vs = Vg + base + (size_t)(kt * 32 + rw) * DM + c0;
#pragma unroll
            for (int j = 0; j < 8; ++j) { Ks[rw][c0 + j] = ks[j]; Vs[rw][c0 + j] = vs[j]; }
        }
        __syncthreads();

        // S = Q K^T  (4 rows x 2 cols per thread)
        float s[4][2] = {{0.f, 0.f}, {0.f, 0.f}, {0.f, 0.f}, {0.f, 0.f}};
#pragma unroll 8
        for (int kk = 0; kk < 64; ++kk) {
            const float a0 = Qs[ty * 4 + 0][kk];
            const float a1 = Qs[ty * 4 + 1][kk];
            const float a2 = Qs[ty * 4 + 2][kk];
            const float a3 = Qs[ty * 4 + 3][kk];
            const float c0 = Ks[tx * 2 + 0][kk];
            const float c1 = Ks[tx * 2 + 1][kk];
            s[0][0] = fmaf(a0, c0, s[0][0]); s[0][1] = fmaf(a0, c1, s[0][1]);
            s[1][0] = fmaf(a1, c0, s[1][0]); s[1][1] = fmaf(a1, c1, s[1][1]);
            s[2][0] = fmaf(a2, c0, s[2][0]); s[2][1] = fmaf(a2, c1, s[2][1]);
            s[3][0] = fmaf(a3, c0, s[3][0]); s[3][1] = fmaf(a3, c1, s[3][1]);
        }
        // scale + causal mask
#pragma unroll
        for (int i = 0; i < 4; ++i) {
            const int qg = qt * 64 + ty * 4 + i;
#pragma unroll
            for (int j = 0; j < 2; ++j) {
                const int jg = kt * 32 + tx * 2 + j;
                s[i][j] = (jg <= qg) ? s[i][j] * 0.125f : -INFINITY;
            }
        }
        // row max partials
#pragma unroll
        for (int i = 0; i < 4; ++i)
            red[ty * 4 + i][tx] = fmaxf(s[i][0], s[i][1]);
        __syncthreads();
        if (tid < 64) {
            const float mold = mrow[tid];
            float mn = mold;
#pragma unroll
            for (int t2 = 0; t2 < 16; ++t2) mn = fmaxf(mn, red[tid][t2]);
            mrow[tid] = mn;
            arow[tid] = __expf(mold - mn);   // first tile: exp(-inf - finite) = 0
        }
        __syncthreads();
        // p = exp(s - m), stash to LDS, partial row sums
#pragma unroll
        for (int i = 0; i < 4; ++i) {
            const float m = mrow[ty * 4 + i];
            const float p0 = __expf(s[i][0] - m);
            const float p1 = __expf(s[i][1] - m);
            Ps[ty * 4 + i][tx * 2 + 0] = p0;
            Ps[ty * 4 + i][tx * 2 + 1] = p1;
            red[ty * 4 + i][tx] = p0 + p1;
        }
        __syncthreads();
        if (tid < 64) {
            float ls = 0.f;
#pragma unroll
            for (int t2 = 0; t2 < 16; ++t2) ls += red[tid][t2];
            lrow[tid] = lrow[tid] * arow[tid] + ls;
        }
        // rescale O and accumulate P V
        float al[4];
#pragma unroll
        for (int i = 0; i < 4; ++i) al[i] = arow[ty * 4 + i];
#pragma unroll
        for (int i = 0; i < 4; ++i)
#pragma unroll
            for (int j = 0; j < 4; ++j) oacc[i][j] *= al[i];
#pragma unroll 8
        for (int j = 0; j < 32; ++j) {
            const float p0 = Ps[ty * 4 + 0][j];
            const float p1 = Ps[ty * 4 + 1][j];
            const float p2 = Ps[ty * 4 + 2][j];
            const float p3 = Ps[ty * 4 + 3][j];
            const float v0 = Vs[j][tx * 4 + 0];
            const float v1 = Vs[j][tx * 4 + 1];
            const float v2 = Vs[j][tx * 4 + 2];
            const float v3 = Vs[j][tx * 4 + 3];
            oacc[0][0] = fmaf(p0, v0, oacc[0][0]); oacc[0][1] = fmaf(p0, v1, oacc[0][1]);
            oacc[0][2] = fmaf(p0, v2, oacc[0][2]); oacc[0][3] = fmaf(p0, v3, oacc[0][3]);
            oacc[1][0] = fmaf(p1, v0, oacc[1][0]); oacc[1][1] = fmaf(p1, v1, oacc[1][1]);
            oacc[1][2] = fmaf(p1, v2, oacc[1][2]); oacc[1][3] = fmaf(p1, v3, oacc[1][3]);
            oacc[2][0] = fmaf(p2, v0, oacc[2][0]); oacc[2][1] = fmaf(p2, v1, oacc[2][1]);
            oacc[2][2] = fmaf(p2, v2, oacc[2][2]); oacc[2][3] = fmaf(p2, v3, oacc[2][3]);
            oacc[3][0] = fmaf(p3, v0, oacc[3][0]); oacc[3][1] = fmaf(p3, v1, oacc[3][1]);
            oacc[3][2] = fmaf(p3, v2, oacc[3][2]); oacc[3][3] = fmaf(p3, v3, oacc[3][3]);
        }
    }
    __syncthreads();
#pragma unroll
    for (int i = 0; i < 4; ++i) {
        const float inv = 1.f / lrow[ty * 4 + i];
        float4 o = {oacc[i][0] * inv, oacc[i][1] * inv, oacc[i][2] * inv, oacc[i][3] * inv};
        *(float4*)(Og + base + (size_t)(qt * 64 + ty * 4 + i) * DM + tx * 4) = o;
    }
}

// ---------------------------------------------------------------- layernorm
// out = LN(x + res) * s + b   (row length DM=512, one block per row)
__global__ __launch_bounds__(256) void ln_kernel(
    const float* __restrict__ x, const float* __restrict__ res,
    const float* __restrict__ s, const float* __restrict__ b,
    float* __restrict__ out)
{
    __shared__ float sred[256];
    const int t = blockIdx.x;
    const int i0 = threadIdx.x;
    const int i1 = threadIdx.x + 256;
    const float* xp = x + (size_t)t * DM;
    const float* rp = res + (size_t)t * DM;
    const float v0 = xp[i0] + rp[i0];
    const float v1 = xp[i1] + rp[i1];
    sred[i0] = v0 + v1;
    __syncthreads();
    for (int st = 128; st > 0; st >>= 1) {
        if (i0 < st) sred[i0] += sred[i0 + st];
        __syncthreads();
    }
    const float mu = sred[0] * (1.f / DM);
    __syncthreads();
    const float d0 = v0 - mu, d1 = v1 - mu;
    sred[i0] = d0 * d0 + d1 * d1;
    __syncthreads();
    for (int st = 128; st > 0; st >>= 1) {
        if (i0 < st) sred[i0] += sred[i0 + st];
        __syncthreads();
    }
    const float rstd = rsqrtf(sred[0] * (1.f / DM) + 1e-5f);
    float* op = out + (size_t)t * DM;
    op[i0] = d0 * rstd * s[i0] + b[i0];
    op[i1] = d1 * rstd * s[i1] + b[i1];
}

// ---------------------------------------------------------------- head gather
__global__ __launch_bounds__(256) void gather_kernel(
    const float* __restrict__ ctx, const float* __restrict__ val,
    const float* __restrict__ skill, const int* __restrict__ q,
    float* __restrict__ feat)
{
    const int t = blockIdx.x;
    const float* sp = skill + (size_t)q[t] * DM;
    const float* cp = ctx + (size_t)t * DM;
    const float* vp = val + (size_t)t * DM;
    float* fp = feat + (size_t)t * (3 * DM);
    for (int d = threadIdx.x; d < DM; d += 256) {
        fp[d] = cp[d];
        fp[DM + d] = vp[d];
        fp[2 * DM + d] = sp[d];
    }
}

// ---------------------------------------------------------------- logits
__global__ __launch_bounds__(256) void logits_kernel(
    const float* __restrict__ h2, const float* __restrict__ w,
    const float* __restrict__ bptr, float* __restrict__ out)
{
    __shared__ float sred[256];
    const int t = blockIdx.x;
    sred[threadIdx.x] = h2[(size_t)t * 256 + threadIdx.x] * w[threadIdx.x];
    __syncthreads();
    for (int st = 128; st > 0; st >>= 1) {
        if (threadIdx.x < st) sred[threadIdx.x] += sred[threadIdx.x + st];
        __syncthreads();
    }
    if (threadIdx.x == 0) {
        const float logit = sred[0] + bptr[0];
        out[t] = 1.f / (1.f + __expf(-logit));
    }
}

// ---------------------------------------------------------------- launch
extern "C" void kernel_launch(void* const* d_in, const int* in_sizes, int n_in,
                              void* d_out, int out_size, void* d_ws, size_t ws_size,
                              hipStream_t stream)
{
    const int*   q         = (const int*)d_in[0];
    const int*   r         = (const int*)d_in[1];
    const float* ctx_emb   = (const float*)d_in[2];
    const float* val_emb   = (const float*)d_in[3];
    const float* skill_emb = (const float*)d_in[4];
    const float* pos_emb   = (const float*)d_in[5];
    const float* Wq = (const float*)d_in[6];
    const float* bq = (const float*)d_in[7];
    const float* Wk = (const float*)d_in[8];
    const float* bk = (const float*)d_in[9];
    const float* Wv = (const float*)d_in[10];
    const float* bv = (const float*)d_in[11];
    const float* Wo = (const float*)d_in[12];
    const float* bo = (const float*)d_in[13];
    const float* ln1c_s = (const float*)d_in[14];
    const float* ln1c_b = (const float*)d_in[15];
    const float* ln1v_s = (const float*)d_in[16];
    const float* ln1v_b = (const float*)d_in[17];
    const float* ln2c_s = (const float*)d_in[18];
    const float* ln2c_b = (const float*)d_in[19];
    const float* ln2v_s = (const float*)d_in[20];
    const float* ln2v_b = (const float*)d_in[21];
    const float* fc1c_W = (const float*)d_in[22];
    const float* fc1c_b = (const float*)d_in[23];
    const float* fc2c_W = (const float*)d_in[24];
    const float* fc2c_b = (const float*)d_in[25];
    const float* fc1v_W = (const float*)d_in[26];
    const float* fc1v_b = (const float*)d_in[27];
    const float* fc2v_W = (const float*)d_in[28];
    const float* fc2v_b = (const float*)d_in[29];
    const float* hW1 = (const float*)d_in[30];
    const float* hb1 = (const float*)d_in[31];
    const float* hW2 = (const float*)d_in[32];
    const float* hb2 = (const float*)d_in[33];
    const float* hW3 = (const float*)d_in[34];
    const float* hb3 = (const float*)d_in[35];
    float* out = (float*)d_out;

    float* ws = (float*)d_ws;
    const size_t SZ = (size_t)TOK * DM;   // 4,194,304 floats
    float* ctx = ws;
    float* val = ws + SZ;
    float* Qb  = ws + 2 * SZ;
    float* Kb  = ws + 3 * SZ;
    float* Vb  = ws + 4 * SZ;
    float* att = ws + 5 * SZ;
    float* ob  = ws + 6 * SZ;
    float* mid = ws + 7 * SZ;             // TOK*DFFN floats
    float* feat = Qb;                     // reuses Q..V (3*SZ = TOK*1536) after loop
    float* h2  = att;                     // reuses att after loop

    embed_kernel<<<TOK, 256, 0, stream>>>(q, r, ctx_emb, val_emb, pos_emb, ctx, val);

    auto gemm = [&](const float* A, const float* W, const float* bias, float* C,
                    int M, int N, int K, int relu) {
        gemm_kernel<<<dim3(N / 128, M / 128), 256, 0, stream>>>(A, W, bias, C, M, N, K, relu);
    };

    for (int i = 0; i < NBLK; ++i) {
        gemm(ctx, Wq + (size_t)i * DM * DM, bq + i * DM, Qb, TOK, DM, DM, 0);
        gemm(ctx, Wk + (size_t)i * DM * DM, bk + i * DM, Kb, TOK, DM, DM, 0);
        gemm(val, Wv + (size_t)i * DM * DM, bv + i * DM, Vb, TOK, DM, DM, 0);
        attn_kernel<<<dim3(SEQ / 64, 64), 256, 0, stream>>>(Qb, Kb, Vb, att);
        gemm(att, Wo + (size_t)i * DM * DM, bo + i * DM, ob, TOK, DM, DM, 0);
        ln_kernel<<<TOK, 256, 0, stream>>>(ctx, ob, ln1c_s + i * DM, ln1c_b + i * DM, ctx);
        ln_kernel<<<TOK, 256, 0, stream>>>(val, ob, ln1v_s + i * DM, ln1v_b + i * DM, val);
        gemm(ctx, fc1c_W + (size_t)i * DM * DFFN, fc1c_b + i * DFFN, mid, TOK, DFFN, DM, 1);
        gemm(mid, fc2c_W + (size_t)i * DFFN * DM, fc2c_b + i * DM, ob, TOK, DM, DFFN, 0);
        ln_kernel<<<TOK, 256, 0, stream>>>(ctx, ob, ln2c_s + i * DM, ln2c_b + i * DM, ctx);
        gemm(val, fc1v_W + (size_t)i * DM * DFFN, fc1v_b + i * DFFN, mid, TOK, DFFN, DM, 1);
        gemm(mid, fc2v_W + (size_t)i * DFFN * DM, fc2v_b + i * DM, ob, TOK, DM, DFFN, 0);
        ln_kernel<<<TOK, 256, 0, stream>>>(val, ob, ln2v_s + i * DM, ln2v_b + i * DM, val);
    }

    gather_kernel<<<TOK, 256, 0, stream>>>(ctx, val, skill_emb, q, feat);
    gemm(feat, hW1, hb1, mid, TOK, DFFN, 3 * DM, 1);   // h1 = relu(feat@hW1+hb1)
    gemm(mid, hW2, hb2, h2, TOK, 256, DFFN, 1);        // h2 = relu(h1@hW2+hb2)
    logits_kernel<<<TOK, 256, 0, stream>>>(h2, hW3, hb3, out);
}

// Round 2
// 2773.713 us; speedup vs baseline: 2.7699x; 2.7699x over previous
//
#include <hip/hip_runtime.h>
#include <hip/hip_bf16.h>
#include <math.h>

#define TOK 8192   // B*L
#define DM 512
#define NH 8
#define DKH 64
#define DFFN 2048
#define SEQ 1024
#define NBLK 4
#define NUMC 1000

typedef __attribute__((ext_vector_type(8))) short bf16x8;
typedef __attribute__((ext_vector_type(4))) float f32x4;
typedef __hip_bfloat16 bf16;

__device__ __forceinline__ void gload_lds16(const ushort* g, ushort* l) {
    __builtin_amdgcn_global_load_lds(
        (const __attribute__((address_space(1))) void*)g,
        (__attribute__((address_space(3))) void*)l, 16, 0, 0);
}

// ---------------------------------------------------------------- embed
__global__ __launch_bounds__(256) void embed_kernel(
    const int* __restrict__ q, const int* __restrict__ r,
    const float* __restrict__ ctx_emb, const float* __restrict__ val_emb,
    const float* __restrict__ pos_emb,
    float* __restrict__ ctx32, float* __restrict__ val32,
    bf16* __restrict__ ctx16, bf16* __restrict__ val16)
{
    const int t = blockIdx.x;
    const int inter = q[t] + NUMC * r[t];
    const int l = t & (SEQ - 1);
    const float* ce = ctx_emb + (size_t)inter * DM;
    const float* ve = val_emb + (size_t)inter * DM;
    const float* pe = pos_emb + (size_t)l * DM;
    const size_t o = (size_t)t * DM;
    for (int d = threadIdx.x; d < DM; d += 256) {
        float p = pe[d];
        float c = ce[d] + p;
        float v = ve[d] + p;
        ctx32[o + d] = c; val32[o + d] = v;
        ctx16[o + d] = __float2bfloat16(c);
        val16[o + d] = __float2bfloat16(v);
    }
}

// ---------------------------------------------------------------- transpose+cvt
// dst[n][k] = bf16(src[k][n]); src [K][N] fp32, dst row stride K.
__global__ __launch_bounds__(256) void transpose_kernel(
    const float* __restrict__ src, bf16* __restrict__ dst,
    int K, int N, long sb, long db)
{
    __shared__ float t[32][33];
    src += (long)blockIdx.z * sb;
    dst += (long)blockIdx.z * db;
    const int n0 = blockIdx.x * 32;
    const int k0 = blockIdx.y * 32;
    const int tx = threadIdx.x;            // 0..31
    const int ty = threadIdx.y;            // 0..7
    for (int i = ty; i < 32; i += 8) t[i][tx] = src[(size_t)(k0 + i) * N + n0 + tx];
    __syncthreads();
    for (int i = ty; i < 32; i += 8)
        dst[(size_t)(n0 + i) * K + k0 + tx] = __float2bfloat16(t[tx][i]);
}

// ---------------------------------------------------------------- MFMA GEMM
// C[M,N] = A[M,K](bf16) @ Bt[N,K](bf16)^T + bias, opt ReLU.
// 128 x BN tile, BK=32, 256 thr (4 waves), global_load_lds width-16 staging.
template<int BN, bool OUTBF16>
__global__ __launch_bounds__(256, 2) void mfma_gemm(
    const ushort* __restrict__ A, const ushort* __restrict__ Bt,
    const float* __restrict__ bias1, const float* __restrict__ bias2, int split,
    void* __restrict__ Cv, int N, int K, int relu)
{
    constexpr int MI = (BN == 128) ? 4 : 2;
    __shared__ ushort As[128 * 32];
    __shared__ ushort Bs[BN * 32];
    const int tid = threadIdx.x;
    const int wave = tid >> 6;
    const int lane = tid & 63;
    const int ln = lane & 15;
    const int kq = lane >> 4;
    const int bm = blockIdx.y * 128;
    const int bn = blockIdx.x * BN;
    const int wr = (BN == 128) ? (wave >> 1) * 64 : wave * 32;
    const int wc = (BN == 128) ? (wave & 1) * 64 : 0;

    // staging: thread tid moves 8 bf16 (16B); row = tid/4, kcol = (tid%4)*8
    const int srow = tid >> 2;
    const int scol = (tid & 3) * 8;
    const ushort* Ag0 = A + (size_t)(bm + srow) * K + scol;
    const ushort* Ag1 = A + (size_t)(bm + 64 + srow) * K + scol;
    const ushort* Bg0 = Bt + (size_t)(bn + srow) * K + scol;
    const ushort* Bg1 = (BN == 128) ? (Bt + (size_t)(bn + 64 + srow) * K + scol) : nullptr;
    ushort* AsW0 = As + wave * 512;          // wave-uniform; dest = base + lane*16B
    ushort* AsW1 = As + 2048 + wave * 512;
    ushort* BsW0 = Bs + wave * 512;
    ushort* BsW1 = Bs + 2048 + wave * 512;   // only used when BN==128

    f32x4 acc[MI][4];
#pragma unroll
    for (int i = 0; i < MI; ++i)
#pragma unroll
        for (int j = 0; j < 4; ++j) acc[i][j] = (f32x4){0.f, 0.f, 0.f, 0.f};

    for (int k0 = 0; k0 < K; k0 += 32) {
        __syncthreads();   // all waves done reading LDS of prev tile
        gload_lds16(Ag0 + k0, AsW0);
        gload_lds16(Ag1 + k0, AsW1);
        gload_lds16(Bg0 + k0, BsW0);
        if (BN == 128) gload_lds16(Bg1 + k0, BsW1);
        __syncthreads();   // compiler drains vmcnt before barrier -> staging visible
        bf16x8 bfr[4];
#pragma unroll
        for (int j = 0; j < 4; ++j)
            bfr[j] = *(const bf16x8*)&Bs[(wc + j * 16 + ln) * 32 + kq * 8];
#pragma unroll
        for (int i = 0; i < MI; ++i) {
            const bf16x8 af = *(const bf16x8*)&As[(wr + i * 16 + ln) * 32 + kq * 8];
#pragma unroll
            for (int j = 0; j < 4; ++j)
                acc[i][j] = __builtin_amdgcn_mfma_f32_16x16x32_bf16(af, bfr[j], acc[i][j], 0, 0, 0);
        }
    }

#pragma unroll
    for (int i = 0; i < MI; ++i) {
        const int rowb = bm + wr + i * 16 + kq * 4;
#pragma unroll
        for (int j = 0; j < 4; ++j) {
            const int colg = bn + wc + j * 16 + ln;
            const float bv = (colg < split) ? bias1[colg] : bias2[colg - split];
#pragma unroll
            for (int rr = 0; rr < 4; ++rr) {
                float v = acc[i][j][rr] + bv;
                if (relu) v = fmaxf(v, 0.f);
                if (OUTBF16)
                    ((bf16*)Cv)[(size_t)(rowb + rr) * N + colg] = __float2bfloat16(v);
                else
                    ((float*)Cv)[(size_t)(rowb + rr) * N + colg] = v;
            }
        }
    }
}

// ---------------------------------------------------------------- attention
// One block per (b, h, 64-row q-tile); fp32 math, bf16 I/O.
// Q at qk[t][h*64+d], K at qk[t][512+h*64+d] (row stride 1024), V [t][512].
__global__ __launch_bounds__(256) void attn_kernel(
    const bf16* __restrict__ QK, const bf16* __restrict__ Vg,
    bf16* __restrict__ Og)
{
    __shared__ float Qs[64][65];
    __shared__ float Ks[32][65];
    __shared__ float Vs[32][65];
    __shared__ float Ps[64][33];
    __shared__ float red[64][17];
    __shared__ float mrow[64];
    __shared__ float lrow[64];
    __shared__ float arow[64];

    const int tid = threadIdx.x;
    const int tx = tid & 15;
    const int ty = tid >> 4;
    const int qt = blockIdx.x;
    const int b = blockIdx.y >> 3;
    const int h = blockIdx.y & 7;
    const int hc = h * DKH;

    {
        const int rw = tid >> 2;
        const int c0 = (tid & 3) * 16;
        const bf16* src = QK + (size_t)(b * SEQ + qt * 64 + rw) * 1024 + hc + c0;
#pragma unroll
        for (int j = 0; j < 16; ++j) Qs[rw][c0 + j] = __bfloat162float(src[j]);
    }
    if (tid < 64) { mrow[tid] = -INFINITY; lrow[tid] = 0.f; }

    float oacc[4][4];
#pragma unroll
    for (int i = 0; i < 4; ++i)
#pragma unroll
        for (int j = 0; j < 4; ++j) oacc[i][j] = 0.f;

    const int nkt = 2 * qt + 2;
    for (int kt = 0; kt < nkt; ++kt) {
        __syncthreads();
        {
            const int rw = tid >> 3;
            const int c0 = (tid & 7) * 8;
            const int row = b * SEQ + kt * 32 + rw;
            const bf16* ks = QK + (size_t)row * 1024 + 512 + hc + c0;
            const bf16* vs = Vg + (size_t)row * 512 + hc + c0;
#pragma unroll
            for (int j = 0; j < 8; ++j) {
                Ks[rw][c0 + j] = __bfloat162float(ks[j]);
                Vs[rw][c0 + j] = __bfloat162float(vs[j]);
            }
        }
        __syncthreads();

        float s[4][2] = {{0.f, 0.f}, {0.f, 0.f}, {0.f, 0.f}, {0.f, 0.f}};
#pragma unroll 8
        for (int kk = 0; kk < 64; ++kk) {
            const float a0 = Qs[ty * 4 + 0][kk];
            const float a1 = Qs[ty * 4 + 1][kk];
            const float a2 = Qs[ty * 4 + 2][kk];
            const float a3 = Qs[ty * 4 + 3][kk];
            const float c0 = Ks[tx * 2 + 0][kk];
            const float c1 = Ks[tx * 2 + 1][kk];
            s[0][0] = fmaf(a0, c0, s[0][0]); s[0][1] = fmaf(a0, c1, s[0][1]);
            s[1][0] = fmaf(a1, c0, s[1][0]); s[1][1] = fmaf(a1, c1, s[1][1]);
            s[2][0] = fmaf(a2, c0, s[2][0]); s[2][1] = fmaf(a2, c1, s[2][1]);
            s[3][0] = fmaf(a3, c0, s[3][0]); s[3][1] = fmaf(a3, c1, s[3][1]);
        }
#pragma unroll
        for (int i = 0; i < 4; ++i) {
            const int qg = qt * 64 + ty * 4 + i;
#pragma unroll
            for (int j = 0; j < 2; ++j) {
                const int jg = kt * 32 + tx * 2 + j;
                s[i][j] = (jg <= qg) ? s[i][j] * 0.125f : -INFINITY;
            }
        }
#pragma unroll
        for (int i = 0; i < 4; ++i)
            red[ty * 4 + i][tx] = fmaxf(s[i][0], s[i][1]);
        __syncthreads();
        if (tid < 64) {
            const float mold = mrow[tid];
            float mn = mold;
#pragma unroll
            for (int t2 = 0; t2 < 16; ++t2) mn = fmaxf(mn, red[tid][t2]);
            mrow[tid] = mn;
            arow[tid] = __expf(mold - mn);
        }
        __syncthreads();
#pragma unroll
        for (int i = 0; i < 4; ++i) {
            const float m = mrow[ty * 4 + i];
            const float p0 = __expf(s[i][0] - m);
            const float p1 = __expf(s[i][1] - m);
            Ps[ty * 4 + i][tx * 2 + 0] = p0;
            Ps[ty * 4 + i][tx * 2 + 1] = p1;
            red[ty * 4 + i][tx] = p0 + p1;
        }
        __syncthreads();
        if (tid < 64) {
            float ls = 0.f;
#pragma unroll
            for (int t2 = 0; t2 < 16; ++t2) ls += red[tid][t2];
            lrow[tid] = lrow[tid] * arow[tid] + ls;
        }
        float al[4];
#pragma unroll
        for (int i = 0; i < 4; ++i) al[i] = arow[ty * 4 + i];
#pragma unroll
        for (int i = 0; i < 4; ++i)
#pragma unroll
            for (int j = 0; j < 4; ++j) oacc[i][j] *= al[i];
#pragma unroll 8
        for (int j = 0; j < 32; ++j) {
            const float p0 = Ps[ty * 4 + 0][j];
            const float p1 = Ps[ty * 4 + 1][j];
            const float p2 = Ps[ty * 4 + 2][j];
            const float p3 = Ps[ty * 4 + 3][j];
            const float v0 = Vs[j][tx * 4 + 0];
            const float v1 = Vs[j][tx * 4 + 1];
            const float v2 = Vs[j][tx * 4 + 2];
            const float v3 = Vs[j][tx * 4 + 3];
            oacc[0][0] = fmaf(p0, v0, oacc[0][0]); oacc[0][1] = fmaf(p0, v1, oacc[0][1]);
            oacc[0][2] = fmaf(p0, v2, oacc[0][2]); oacc[0][3] = fmaf(p0, v3, oacc[0][3]);
            oacc[1][0] = fmaf(p1, v0, oacc[1][0]); oacc[1][1] = fmaf(p1, v1, oacc[1][1]);
            oacc[1][2] = fmaf(p1, v2, oacc[1][2]); oacc[1][3] = fmaf(p1, v3, oacc[1][3]);
            oacc[2][0] = fmaf(p2, v0, oacc[2][0]); oacc[2][1] = fmaf(p2, v1, oacc[2][1]);
            oacc[2][2] = fmaf(p2, v2, oacc[2][2]); oacc[2][3] = fmaf(p2, v3, oacc[2][3]);
            oacc[3][0] = fmaf(p3, v0, oacc[3][0]); oacc[3][1] = fmaf(p3, v1, oacc[3][1]);
            oacc[3][2] = fmaf(p3, v2, oacc[3][2]); oacc[3][3] = fmaf(p3, v3, oacc[3][3]);
        }
    }
    __syncthreads();
#pragma unroll
    for (int i = 0; i < 4; ++i) {
        const float inv = 1.f / lrow[ty * 4 + i];
        bf16* og = Og + (size_t)(b * SEQ + qt * 64 + ty * 4 + i) * 512 + hc + tx * 4;
#pragma unroll
        for (int j = 0; j < 4; ++j) og[j] = __float2bfloat16(oacc[i][j] * inv);
    }
}

// ---------------------------------------------------------------- layernorm
// out = LN(x32 + res16) * s + b, writes fp32 + bf16
__global__ __launch_bounds__(256) void ln_kernel(
    const float* __restrict__ x, const bf16* __restrict__ res,
    const float* __restrict__ s, const float* __restrict__ b,
    float* __restrict__ out32, bf16* __restrict__ out16)
{
    __shared__ float w1[4], w2[4];
    const size_t o = (size_t)blockIdx.x * DM;
    const int i0 = threadIdx.x, i1 = threadIdx.x + 256;
    const float v0 = x[o + i0] + __bfloat162float(res[o + i0]);
    const float v1 = x[o + i1] + __bfloat162float(res[o + i1]);
    float sum = v0 + v1;
#pragma unroll
    for (int off = 32; off; off >>= 1) sum += __shfl_down(sum, off);
    if ((threadIdx.x & 63) == 0) w1[threadIdx.x >> 6] = sum;
    __syncthreads();
    const float mu = (w1[0] + w1[1] + w1[2] + w1[3]) * (1.f / DM);
    const float d0 = v0 - mu, d1 = v1 - mu;
    float vs = d0 * d0 + d1 * d1;
#pragma unroll
    for (int off = 32; off; off >>= 1) vs += __shfl_down(vs, off);
    if ((threadIdx.x & 63) == 0) w2[threadIdx.x >> 6] = vs;
    __syncthreads();
    const float rstd = rsqrtf((w2[0] + w2[1] + w2[2] + w2[3]) * (1.f / DM) + 1e-5f);
    const float o0 = d0 * rstd * s[i0] + b[i0];
    const float o1 = d1 * rstd * s[i1] + b[i1];
    out32[o + i0] = o0; out32[o + i1] = o1;
    out16[o + i0] = __float2bfloat16(o0);
    out16[o + i1] = __float2bfloat16(o1);
}

// ---------------------------------------------------------------- head gather
__global__ __launch_bounds__(256) void gather_kernel(
    const bf16* __restrict__ ctx16, const bf16* __restrict__ val16,
    const float* __restrict__ skill, const int* __restrict__ q,
    bf16* __restrict__ feat)
{
    const int t = blockIdx.x;
    const float* sp = skill + (size_t)q[t] * DM;
    const bf16* cp = ctx16 + (size_t)t * DM;
    const bf16* vp = val16 + (size_t)t * DM;
    bf16* fp = feat + (size_t)t * (3 * DM);
    for (int d = threadIdx.x; d < DM; d += 256) {
        fp[d] = cp[d];
        fp[DM + d] = vp[d];
        fp[2 * DM + d] = __float2bfloat16(sp[d]);
    }
}

// ---------------------------------------------------------------- logits
__global__ __launch_bounds__(256) void logits_kernel(
    const float* __restrict__ h2, const float* __restrict__ w,
    const float* __restrict__ bptr, float* __restrict__ out)
{
    __shared__ float w1[4];
    const int t = blockIdx.x;
    float sum = h2[(size_t)t * 256 + threadIdx.x] * w[threadIdx.x];
#pragma unroll
    for (int off = 32; off; off >>= 1) sum += __shfl_down(sum, off);
    if ((threadIdx.x & 63) == 0) w1[threadIdx.x >> 6] = sum;
    __syncthreads();
    if (threadIdx.x == 0) {
        const float logit = w1[0] + w1[1] + w1[2] + w1[3] + bptr[0];
        out[t] = 1.f / (1.f + __expf(-logit));
    }
}

// ---------------------------------------------------------------- launch
extern "C" void kernel_launch(void* const* d_in, const int* in_sizes, int n_in,
                              void* d_out, int out_size, void* d_ws, size_t ws_size,
                              hipStream_t stream)
{
    const int*   q         = (const int*)d_in[0];
    const int*   r         = (const int*)d_in[1];
    const float* ctx_emb   = (const float*)d_in[2];
    const float* val_emb   = (const float*)d_in[3];
    const float* skill_emb = (const float*)d_in[4];
    const float* pos_emb   = (const float*)d_in[5];
    const float* Wq = (const float*)d_in[6];
    const float* bq = (const float*)d_in[7];
    const float* Wk = (const float*)d_in[8];
    const float* bk = (const float*)d_in[9];
    const float* Wv = (const float*)d_in[10];
    const float* bv = (const float*)d_in[11];
    const float* Wo = (const float*)d_in[12];
    const float* bo = (const float*)d_in[13];
    const float* ln1c_s = (const float*)d_in[14];
    const float* ln1c_b = (const float*)d_in[15];
    const float* ln1v_s = (const float*)d_in[16];
    const float* ln1v_b = (const float*)d_in[17];
    const float* ln2c_s = (const float*)d_in[18];
    const float* ln2c_b = (const float*)d_in[19];
    const float* ln2v_s = (const float*)d_in[20];
    const float* ln2v_b = (const float*)d_in[21];
    const float* fc1c_W = (const float*)d_in[22];
    const float* fc1c_b = (const float*)d_in[23];
    const float* fc2c_W = (const float*)d_in[24];
    const float* fc2c_b = (const float*)d_in[25];
    const float* fc1v_W = (const float*)d_in[26];
    const float* fc1v_b = (const float*)d_in[27];
    const float* fc2v_W = (const float*)d_in[28];
    const float* fc2v_b = (const float*)d_in[29];
    const float* hW1 = (const float*)d_in[30];
    const float* hb1 = (const float*)d_in[31];
    const float* hW2 = (const float*)d_in[32];
    const float* hb2 = (const float*)d_in[33];
    const float* hW3 = (const float*)d_in[34];
    const float* hb3 = (const float*)d_in[35];
    float* out = (float*)d_out;

    char* p = (char*)d_ws;
    auto alloc = [&](size_t bytes) { char* ret = p; p += bytes; return ret; };
    float* ctx32 = (float*)alloc(16777216);
    float* val32 = (float*)alloc(16777216);
    bf16*  ob16  = (bf16*)alloc(8388608);
    bf16*  ctx16 = (bf16*)alloc(8388608);
    bf16*  val16 = (bf16*)alloc(8388608);
    bf16*  qk16  = (bf16*)alloc(16777216);   // [8192][1024]
    bf16*  v16   = (bf16*)alloc(8388608);
    bf16*  att16 = (bf16*)alloc(8388608);
    bf16*  mid16 = (bf16*)alloc(33554432);   // [8192][2048]
    bf16*  qkT   = (bf16*)alloc(4194304);    // [4][1024][512]
    bf16*  vT    = (bf16*)alloc(2097152);    // [4][512][512]
    bf16*  oT    = (bf16*)alloc(2097152);
    bf16*  fc1cT = (bf16*)alloc(8388608);    // [4][2048][512]
    bf16*  fc2cT = (bf16*)alloc(8388608);    // [4][512][2048]
    bf16*  fc1vT = (bf16*)alloc(8388608);
    bf16*  fc2vT = (bf16*)alloc(8388608);
    bf16*  hW1T  = (bf16*)alloc(6291456);    // [2048][1536]
    bf16*  hW2T  = (bf16*)alloc(1048576);    // [256][2048]
    bf16*  feat16 = qk16;                    // reuse qk16+v16 (25.2MB) after blocks
    float* h2     = (float*)att16;           // reuse att16 (8.4MB) as fp32 [8192][256]

    const dim3 tb(32, 8);
    // weight transposes (fp32 [K][N] -> bf16 [N][K])
    transpose_kernel<<<dim3(16, 16, 4), tb, 0, stream>>>(Wq, qkT,          512, 512, 262144, 524288);
    transpose_kernel<<<dim3(16, 16, 4), tb, 0, stream>>>(Wk, qkT + 262144, 512, 512, 262144, 524288);
    transpose_kernel<<<dim3(16, 16, 4), tb, 0, stream>>>(Wv, vT, 512, 512, 262144, 262144);
    transpose_kernel<<<dim3(16, 16, 4), tb, 0, stream>>>(Wo, oT, 512, 512, 262144, 262144);
    transpose_kernel<<<dim3(64, 16, 4), tb, 0, stream>>>(fc1c_W, fc1cT, 512, 2048, 1048576, 1048576);
    transpose_kernel<<<dim3(16, 64, 4), tb, 0, stream>>>(fc2c_W, fc2cT, 2048, 512, 1048576, 1048576);
    transpose_kernel<<<dim3(64, 16, 4), tb, 0, stream>>>(fc1v_W, fc1vT, 512, 2048, 1048576, 1048576);
    transpose_kernel<<<dim3(16, 64, 4), tb, 0, stream>>>(fc2v_W, fc2vT, 2048, 512, 1048576, 1048576);
    transpose_kernel<<<dim3(64, 48, 1), tb, 0, stream>>>(hW1, hW1T, 1536, 2048, 0, 0);
    transpose_kernel<<<dim3(8, 64, 1),  tb, 0, stream>>>(hW2, hW2T, 2048, 256, 0, 0);

    embed_kernel<<<TOK, 256, 0, stream>>>(q, r, ctx_emb, val_emb, pos_emb,
                                          ctx32, val32, ctx16, val16);

    for (int i = 0; i < NBLK; ++i) {
        // QK merged: [8192,1024] = ctx16 @ [Wq|Wk]
        mfma_gemm<128, true><<<dim3(8, 64), 256, 0, stream>>>(
            (const ushort*)ctx16, (const ushort*)(qkT + (size_t)i * 524288),
            bq + i * DM, bk + i * DM, 512, qk16, 1024, 512, 0);
        mfma_gemm<64, true><<<dim3(8, 64), 256, 0, stream>>>(
            (const ushort*)val16, (const ushort*)(vT + (size_t)i * 262144),
            bv + i * DM, nullptr, 512, v16, 512, 512, 0);
        attn_kernel<<<dim3(16, 64), 256, 0, stream>>>(qk16, v16, att16);
        mfma_gemm<64, true><<<dim3(8, 64), 256, 0, stream>>>(
            (const ushort*)att16, (const ushort*)(oT + (size_t)i * 262144),
            bo + i * DM, nullptr, 512, ob16, 512, 512, 0);
        ln_kernel<<<TOK, 256, 0, stream>>>(ctx32, ob16, ln1c_s + i * DM, ln1c_b + i * DM, ctx32, ctx16);
        ln_kernel<<<TOK, 256, 0, stream>>>(val32, ob16, ln1v_s + i * DM, ln1v_b + i * DM, val32, val16);
        // ctx FFN
        mfma_gemm<128, true><<<dim3(16, 64), 256, 0, stream>>>(
            (const ushort*)ctx16, (const ushort*)(fc1cT + (size_t)i * 1048576),
            fc1c_b + i * DFFN, nullptr, 2048, mid16, 2048, 512, 1);
        mfma_gemm<64, true><<<dim3(8, 64), 256, 0, stream>>>(
            (const ushort*)mid16, (const ushort*)(fc2cT + (size_t)i * 1048576),
            fc2c_b + i * DM, nullptr, 512, ob16, 512, 2048, 0);
        ln_kernel<<<TOK, 256, 0, stream>>>(ctx32, ob16, ln2c_s + i * DM, ln2c_b + i * DM, ctx32, ctx16);
        // val FFN
        mfma_gemm<128, true><<<dim3(16, 64), 256, 0, stream>>>(
            (const ushort*)val16, (const ushort*)(fc1vT + (size_t)i * 1048576),
            fc1v_b + i * DFFN, nullptr, 2048, mid16, 2048, 512, 1);
        mfma_gemm<64, true><<<dim3(8, 64), 256, 0, stream>>>(
            (const ushort*)mid16, (const ushort*)(fc2vT + (size_t)i * 1048576),
            fc2v_b + i * DM, nullptr, 512, ob16, 512, 2048, 0);
        ln_kernel<<<TOK, 256, 0, stream>>>(val32, ob16, ln2v_s + i * DM, ln2v_b + i * DM, val32, val16);
    }

    gather_kernel<<<TOK, 256, 0, stream>>>(ctx16, val16, skill_emb, q, feat16);
    mfma_gemm<128, true><<<dim3(16, 64), 256, 0, stream>>>(
        (const ushort*)feat16, (const ushort*)hW1T, hb1, nullptr, 2048, mid16, 2048, 1536, 1);
    mfma_gemm<64, false><<<dim3(4, 64), 256, 0, stream>>>(
        (const ushort*)mid16, (const ushort*)hW2T, hb2, nullptr, 256, h2, 256, 2048, 1);
    logits_kernel<<<TOK, 256, 0, stream>>>(h2, hW3, hb3, out);
}

// Round 3
// 1516.515 us; speedup vs baseline: 5.0662x; 1.8290x over previous
//
#include <hip/hip_runtime.h>
#include <hip/hip_bf16.h>
#include <math.h>

#define TOK 8192   // B*L
#define DM 512
#define NH 8
#define DKH 64
#define DFFN 2048
#define SEQ 1024
#define NBLK 4
#define NUMC 1000

typedef __attribute__((ext_vector_type(8))) short bf16x8;
typedef __attribute__((ext_vector_type(4))) float f32x4;
typedef __hip_bfloat16 bf16;

__device__ __forceinline__ void gload_lds16(const ushort* g, ushort* l) {
    __builtin_amdgcn_global_load_lds(
        (const __attribute__((address_space(1))) void*)g,
        (__attribute__((address_space(3))) void*)l, 16, 0, 0);
}

// ---------------------------------------------------------------- embed
__global__ __launch_bounds__(256) void embed_kernel(
    const int* __restrict__ q, const int* __restrict__ r,
    const float* __restrict__ ctx_emb, const float* __restrict__ val_emb,
    const float* __restrict__ pos_emb,
    float* __restrict__ ctx32, float* __restrict__ val32,
    bf16* __restrict__ ctx16, bf16* __restrict__ val16)
{
    const int t = blockIdx.x;
    const int inter = q[t] + NUMC * r[t];
    const int l = t & (SEQ - 1);
    const float* ce = ctx_emb + (size_t)inter * DM;
    const float* ve = val_emb + (size_t)inter * DM;
    const float* pe = pos_emb + (size_t)l * DM;
    const size_t o = (size_t)t * DM;
    for (int d = threadIdx.x; d < DM; d += 256) {
        float p = pe[d];
        float c = ce[d] + p;
        float v = ve[d] + p;
        ctx32[o + d] = c; val32[o + d] = v;
        ctx16[o + d] = __float2bfloat16(c);
        val16[o + d] = __float2bfloat16(v);
    }
}

// ---------------------------------------------------------------- transpose+cvt (weights)
// dst[n][k] = bf16(src[k][n]); src [K][N] fp32, dst row stride K.
__global__ __launch_bounds__(256) void transpose_kernel(
    const float* __restrict__ src, bf16* __restrict__ dst,
    int K, int N, long sb, long db)
{
    __shared__ float t[32][33];
    src += (long)blockIdx.z * sb;
    dst += (long)blockIdx.z * db;
    const int n0 = blockIdx.x * 32;
    const int k0 = blockIdx.y * 32;
    const int tx = threadIdx.x;            // 0..31
    const int ty = threadIdx.y;            // 0..7
    for (int i = ty; i < 32; i += 8) t[i][tx] = src[(size_t)(k0 + i) * N + n0 + tx];
    __syncthreads();
    for (int i = ty; i < 32; i += 8)
        dst[(size_t)(n0 + i) * K + k0 + tx] = __float2bfloat16(t[tx][i]);
}

// ---------------------------------------------------------------- V transpose (bf16)
// in: [8192][512] = [b*1024+key][h*64+d]  ->  out: [(b*8+h)*64+d][1024 keys]
__global__ __launch_bounds__(256) void vtrans_kernel(
    const bf16* __restrict__ in, bf16* __restrict__ outp)
{
    __shared__ ushort T[64 * 66];
    const int ktile = blockIdx.x;   // 16
    const int bh = blockIdx.y;      // 64
    const int b = bh >> 3, h = bh & 7;
    const int t = threadIdx.x;
    const int key = t >> 2, c0 = (t & 3) * 16;
    const bf16* src = in + (size_t)(b * SEQ + ktile * 64 + key) * 512 + h * 64 + c0;
    *(bf16x8*)&T[key * 66 + c0] = *(const bf16x8*)src;
    *(bf16x8*)&T[key * 66 + c0 + 8] = *(const bf16x8*)(src + 8);
    __syncthreads();
    const int d = t >> 2, k0 = (t & 3) * 16;
    bf16x8 w0, w1;
#pragma unroll
    for (int j = 0; j < 8; ++j) w0[j] = ((short*)T)[(k0 + j) * 66 + d];
#pragma unroll
    for (int j = 0; j < 8; ++j) w1[j] = ((short*)T)[(k0 + 8 + j) * 66 + d];
    bf16* dst = outp + (size_t)(bh * 64 + d) * SEQ + ktile * 64 + k0;
    *(bf16x8*)dst = w0;
    *(bf16x8*)(dst + 8) = w1;
}

// ---------------------------------------------------------------- MFMA GEMM
// C[M,N] = A[M,K](bf16) @ Bt[N,K](bf16)^T + bias, opt ReLU.
// 128 x BN tile, BK=32, 256 thr (4 waves), global_load_lds width-16 staging.
// blockIdx.z==1 selects the second (A1,Bt1,bias1_1,Cv1) problem (batched FFN).
template<int BN, bool OUTBF16>
__global__ __launch_bounds__(256, 2) void mfma_gemm(
    const ushort* __restrict__ A, const ushort* __restrict__ Bt,
    const float* __restrict__ bias1, const float* __restrict__ bias2, int split,
    void* __restrict__ Cv, int N, int K, int relu,
    const ushort* __restrict__ A1, const ushort* __restrict__ Bt1,
    const float* __restrict__ bias1_1, void* __restrict__ Cv1)
{
    if (blockIdx.z) { A = A1; Bt = Bt1; bias1 = bias1_1; Cv = Cv1; }
    constexpr int MI = (BN == 128) ? 4 : 2;
    __shared__ ushort As[128 * 32];
    __shared__ ushort Bs[BN * 32];
    const int tid = threadIdx.x;
    const int wave = tid >> 6;
    const int lane = tid & 63;
    const int ln = lane & 15;
    const int kq = lane >> 4;
    const int bm = blockIdx.y * 128;
    const int bn = blockIdx.x * BN;
    const int wr = (BN == 128) ? (wave >> 1) * 64 : wave * 32;
    const int wc = (BN == 128) ? (wave & 1) * 64 : 0;

    const int srow = tid >> 2;
    const int scol = (tid & 3) * 8;
    const ushort* Ag0 = A + (size_t)(bm + srow) * K + scol;
    const ushort* Ag1 = A + (size_t)(bm + 64 + srow) * K + scol;
    const ushort* Bg0 = Bt + (size_t)(bn + srow) * K + scol;
    const ushort* Bg1 = (BN == 128) ? (Bt + (size_t)(bn + 64 + srow) * K + scol) : nullptr;
    ushort* AsW0 = As + wave * 512;
    ushort* AsW1 = As + 2048 + wave * 512;
    ushort* BsW0 = Bs + wave * 512;
    ushort* BsW1 = Bs + 2048 + wave * 512;

    f32x4 acc[MI][4];
#pragma unroll
    for (int i = 0; i < MI; ++i)
#pragma unroll
        for (int j = 0; j < 4; ++j) acc[i][j] = (f32x4){0.f, 0.f, 0.f, 0.f};

    for (int k0 = 0; k0 < K; k0 += 32) {
        __syncthreads();
        gload_lds16(Ag0 + k0, AsW0);
        gload_lds16(Ag1 + k0, AsW1);
        gload_lds16(Bg0 + k0, BsW0);
        if (BN == 128) gload_lds16(Bg1 + k0, BsW1);
        __syncthreads();
        bf16x8 bfr[4];
#pragma unroll
        for (int j = 0; j < 4; ++j)
            bfr[j] = *(const bf16x8*)&Bs[(wc + j * 16 + ln) * 32 + kq * 8];
#pragma unroll
        for (int i = 0; i < MI; ++i) {
            const bf16x8 af = *(const bf16x8*)&As[(wr + i * 16 + ln) * 32 + kq * 8];
#pragma unroll
            for (int j = 0; j < 4; ++j)
                acc[i][j] = __builtin_amdgcn_mfma_f32_16x16x32_bf16(af, bfr[j], acc[i][j], 0, 0, 0);
        }
    }

#pragma unroll
    for (int i = 0; i < MI; ++i) {
        const int rowb = bm + wr + i * 16 + kq * 4;
#pragma unroll
        for (int j = 0; j < 4; ++j) {
            const int colg = bn + wc + j * 16 + ln;
            const float bv = (colg < split) ? bias1[colg] : bias2[colg - split];
#pragma unroll
            for (int rr = 0; rr < 4; ++rr) {
                float v = acc[i][j][rr] + bv;
                if (relu) v = fmaxf(v, 0.f);
                if (OUTBF16)
                    ((bf16*)Cv)[(size_t)(rowb + rr) * N + colg] = __float2bfloat16(v);
                else
                    ((float*)Cv)[(size_t)(rowb + rr) * N + colg] = v;
            }
        }
    }
}

// ---------------------------------------------------------------- MFMA flash attention
// One block per (qt, b*8+h). 4 waves x 16 q-rows, j-tiles of 64 keys.
// QK: [t][1024] (Q cols h*64, K cols 512+h*64); Vt: [(b*8+h)*64+d][1024 keys].
__global__ __launch_bounds__(256) void attn_kernel(
    const bf16* __restrict__ QK, const bf16* __restrict__ Vt,
    bf16* __restrict__ Og)
{
    __shared__ ushort Qs[64 * 68];
    __shared__ ushort Ks[64 * 68];
    __shared__ ushort Vs[64 * 68];      // [dim][key] for current j-tile
    __shared__ ushort Ps[4 * 16 * 68];  // per-wave P (16 q-rows x 64 keys)

    const int tid = threadIdx.x;
    const int wave = tid >> 6, lane = tid & 63;
    const int ln = lane & 15, kq = lane >> 4;
    const int qt = blockIdx.x;
    const int bh = blockIdx.y;
    const int b = bh >> 3, h = bh & 7;

    const int srow = tid >> 2;
    const int sc0 = (tid & 3) * 16;
    {
        const bf16* src = QK + (size_t)(b * SEQ + qt * 64 + srow) * 1024 + h * 64 + sc0;
        *(bf16x8*)&Qs[srow * 68 + sc0] = *(const bf16x8*)src;
        *(bf16x8*)&Qs[srow * 68 + sc0 + 8] = *(const bf16x8*)(src + 8);
    }

    float m2[4], lsum[4];
    f32x4 oacc[4];
#pragma unroll
    for (int r = 0; r < 4; ++r) { m2[r] = -INFINITY; lsum[r] = 0.f; oacc[r] = (f32x4){0.f,0.f,0.f,0.f}; }
    const float sc2 = 0.125f * 1.4426950408889634f;   // 1/sqrt(64) * log2(e)

    for (int kt = 0; kt <= qt; ++kt) {
        __syncthreads();   // prev-iter LDS reads (and initial Q write) complete
        {
            const bf16* ksrc = QK + (size_t)(b * SEQ + kt * 64 + srow) * 1024 + 512 + h * 64 + sc0;
            *(bf16x8*)&Ks[srow * 68 + sc0] = *(const bf16x8*)ksrc;
            *(bf16x8*)&Ks[srow * 68 + sc0 + 8] = *(const bf16x8*)(ksrc + 8);
            const bf16* vsrc = Vt + (size_t)(bh * 64 + srow) * SEQ + kt * 64 + sc0;
            *(bf16x8*)&Vs[srow * 68 + sc0] = *(const bf16x8*)vsrc;
            *(bf16x8*)&Vs[srow * 68 + sc0 + 8] = *(const bf16x8*)(vsrc + 8);
        }
        __syncthreads();

        // S = Q K^T : per wave 16x64, 4 col-tiles x 2 k-halves
        const bf16x8 aq0 = *(const bf16x8*)&Qs[(wave * 16 + ln) * 68 + kq * 8];
        const bf16x8 aq1 = *(const bf16x8*)&Qs[(wave * 16 + ln) * 68 + 32 + kq * 8];
        f32x4 s[4];
#pragma unroll
        for (int c = 0; c < 4; ++c) {
            const bf16x8 bk0 = *(const bf16x8*)&Ks[(c * 16 + ln) * 68 + kq * 8];
            const bf16x8 bk1 = *(const bf16x8*)&Ks[(c * 16 + ln) * 68 + 32 + kq * 8];
            s[c] = (f32x4){0.f, 0.f, 0.f, 0.f};
            s[c] = __builtin_amdgcn_mfma_f32_16x16x32_bf16(aq0, bk0, s[c], 0, 0, 0);
            s[c] = __builtin_amdgcn_mfma_f32_16x16x32_bf16(aq1, bk1, s[c], 0, 0, 0);
        }
        // scale into log2 domain (+ causal mask on the diagonal tile)
        if (kt == qt) {
#pragma unroll
            for (int c = 0; c < 4; ++c)
#pragma unroll
                for (int r = 0; r < 4; ++r) {
                    const int qg = wave * 16 + kq * 4 + r;
                    const int jg = c * 16 + ln;
                    s[c][r] = (jg <= qg) ? s[c][r] * sc2 : -INFINITY;
                }
        } else {
#pragma unroll
            for (int c = 0; c < 4; ++c)
#pragma unroll
                for (int r = 0; r < 4; ++r) s[c][r] *= sc2;
        }
        // online softmax: row reductions via shfl_xor over the 16-lane col group
        float alpha[4];
#pragma unroll
        for (int r = 0; r < 4; ++r) {
            float v = fmaxf(fmaxf(s[0][r], s[1][r]), fmaxf(s[2][r], s[3][r]));
            v = fmaxf(v, __shfl_xor(v, 1));
            v = fmaxf(v, __shfl_xor(v, 2));
            v = fmaxf(v, __shfl_xor(v, 4));
            v = fmaxf(v, __shfl_xor(v, 8));
            const float mn = fmaxf(m2[r], v);
            alpha[r] = exp2f(m2[r] - mn);
            m2[r] = mn;
        }
        float rs[4] = {0.f, 0.f, 0.f, 0.f};
#pragma unroll
        for (int c = 0; c < 4; ++c)
#pragma unroll
            for (int r = 0; r < 4; ++r) {
                const float pv = exp2f(s[c][r] - m2[r]);
                rs[r] += pv;
                // C-layout -> LDS (wave-private region, stride-68: conflict-free)
                *(bf16*)&Ps[wave * 1088 + (kq * 4 + r) * 68 + c * 16 + ln] = __float2bfloat16(pv);
            }
#pragma unroll
        for (int r = 0; r < 4; ++r) {
            float v = rs[r];
            v += __shfl_xor(v, 1);
            v += __shfl_xor(v, 2);
            v += __shfl_xor(v, 4);
            v += __shfl_xor(v, 8);
            lsum[r] = lsum[r] * alpha[r] + v;
        }
#pragma unroll
        for (int c2 = 0; c2 < 4; ++c2)
#pragma unroll
            for (int r = 0; r < 4; ++r) oacc[c2][r] *= alpha[r];
        // P V : P back from LDS in A-layout (same-wave RAW, lgkmcnt handled by compiler)
        const bf16x8 ap0 = *(const bf16x8*)&Ps[wave * 1088 + ln * 68 + kq * 8];
        const bf16x8 ap1 = *(const bf16x8*)&Ps[wave * 1088 + ln * 68 + 32 + kq * 8];
#pragma unroll
        for (int c2 = 0; c2 < 4; ++c2) {
            const bf16x8 bv0 = *(const bf16x8*)&Vs[(c2 * 16 + ln) * 68 + kq * 8];
            const bf16x8 bv1 = *(const bf16x8*)&Vs[(c2 * 16 + ln) * 68 + 32 + kq * 8];
            oacc[c2] = __builtin_amdgcn_mfma_f32_16x16x32_bf16(ap0, bv0, oacc[c2], 0, 0, 0);
            oacc[c2] = __builtin_amdgcn_mfma_f32_16x16x32_bf16(ap1, bv1, oacc[c2], 0, 0, 0);
        }
    }
    float inv[4];
#pragma unroll
    for (int r = 0; r < 4; ++r) inv[r] = 1.f / lsum[r];
#pragma unroll
    for (int c2 = 0; c2 < 4; ++c2)
#pragma unroll
        for (int r = 0; r < 4; ++r)
            Og[(size_t)(b * SEQ + qt * 64 + wave * 16 + kq * 4 + r) * 512 + h * 64 + c2 * 16 + ln]
                = __float2bfloat16(oacc[c2][r] * inv[r]);
}

// ---------------------------------------------------------------- layernorm pair
// out = LN(x + res) * s + b ; blockIdx.y picks problem 0/1.
__global__ __launch_bounds__(256) void lnp_kernel(
    const float* __restrict__ x0, const bf16* __restrict__ r0, const float* __restrict__ s0,
    const float* __restrict__ b0, float* __restrict__ of0, bf16* __restrict__ oh0,
    const float* __restrict__ x1, const bf16* __restrict__ r1, const float* __restrict__ s1,
    const float* __restrict__ b1, float* __restrict__ of1, bf16* __restrict__ oh1)
{
    const float* x = x0; const bf16* res = r0; const float* s = s0; const float* bb = b0;
    float* of = of0; bf16* oh = oh0;
    if (blockIdx.y) { x = x1; res = r1; s = s1; bb = b1; of = of1; oh = oh1; }
    __shared__ float w1[4], w2[4];
    const size_t o = (size_t)blockIdx.x * DM;
    const int i0 = threadIdx.x, i1 = threadIdx.x + 256;
    const float v0 = x[o + i0] + __bfloat162float(res[o + i0]);
    const float v1 = x[o + i1] + __bfloat162float(res[o + i1]);
    float sum = v0 + v1;
#pragma unroll
    for (int off = 32; off; off >>= 1) sum += __shfl_down(sum, off);
    if ((threadIdx.x & 63) == 0) w1[threadIdx.x >> 6] = sum;
    __syncthreads();
    const float mu = (w1[0] + w1[1] + w1[2] + w1[3]) * (1.f / DM);
    const float d0 = v0 - mu, d1 = v1 - mu;
    float vs = d0 * d0 + d1 * d1;
#pragma unroll
    for (int off = 32; off; off >>= 1) vs += __shfl_down(vs, off);
    if ((threadIdx.x & 63) == 0) w2[threadIdx.x >> 6] = vs;
    __syncthreads();
    const float rstd = rsqrtf((w2[0] + w2[1] + w2[2] + w2[3]) * (1.f / DM) + 1e-5f);
    const float o0 = d0 * rstd * s[i0] + bb[i0];
    const float o1 = d1 * rstd * s[i1] + bb[i1];
    of[o + i0] = o0; of[o + i1] = o1;
    oh[o + i0] = __float2bfloat16(o0);
    oh[o + i1] = __float2bfloat16(o1);
}

// ---------------------------------------------------------------- head gather
__global__ __launch_bounds__(256) void gather_kernel(
    const bf16* __restrict__ ctx16, const bf16* __restrict__ val16,
    const float* __restrict__ skill, const int* __restrict__ q,
    bf16* __restrict__ feat)
{
    const int t = blockIdx.x;
    const float* sp = skill + (size_t)q[t] * DM;
    const bf16* cp = ctx16 + (size_t)t * DM;
    const bf16* vp = val16 + (size_t)t * DM;
    bf16* fp = feat + (size_t)t * (3 * DM);
    for (int d = threadIdx.x; d < DM; d += 256) {
        fp[d] = cp[d];
        fp[DM + d] = vp[d];
        fp[2 * DM + d] = __float2bfloat16(sp[d]);
    }
}

// ---------------------------------------------------------------- logits
__global__ __launch_bounds__(256) void logits_kernel(
    const float* __restrict__ h2, const float* __restrict__ w,
    const float* __restrict__ bptr, float* __restrict__ out)
{
    __shared__ float w1[4];
    const int t = blockIdx.x;
    float sum = h2[(size_t)t * 256 + threadIdx.x] * w[threadIdx.x];
#pragma unroll
    for (int off = 32; off; off >>= 1) sum += __shfl_down(sum, off);
    if ((threadIdx.x & 63) == 0) w1[threadIdx.x >> 6] = sum;
    __syncthreads();
    if (threadIdx.x == 0) {
        const float logit = w1[0] + w1[1] + w1[2] + w1[3] + bptr[0];
        out[t] = 1.f / (1.f + __expf(-logit));
    }
}

// ---------------------------------------------------------------- launch
extern "C" void kernel_launch(void* const* d_in, const int* in_sizes, int n_in,
                              void* d_out, int out_size, void* d_ws, size_t ws_size,
                              hipStream_t stream)
{
    const int*   q         = (const int*)d_in[0];
    const int*   r         = (const int*)d_in[1];
    const float* ctx_emb   = (const float*)d_in[2];
    const float* val_emb   = (const float*)d_in[3];
    const float* skill_emb = (const float*)d_in[4];
    const float* pos_emb   = (const float*)d_in[5];
    const float* Wq = (const float*)d_in[6];
    const float* bq = (const float*)d_in[7];
    const float* Wk = (const float*)d_in[8];
    const float* bk = (const float*)d_in[9];
    const float* Wv = (const float*)d_in[10];
    const float* bv = (const float*)d_in[11];
    const float* Wo = (const float*)d_in[12];
    const float* bo = (const float*)d_in[13];
    const float* ln1c_s = (const float*)d_in[14];
    const float* ln1c_b = (const float*)d_in[15];
    const float* ln1v_s = (const float*)d_in[16];
    const float* ln1v_b = (const float*)d_in[17];
    const float* ln2c_s = (const float*)d_in[18];
    const float* ln2c_b = (const float*)d_in[19];
    const float* ln2v_s = (const float*)d_in[20];
    const float* ln2v_b = (const float*)d_in[21];
    const float* fc1c_W = (const float*)d_in[22];
    const float* fc1c_b = (const float*)d_in[23];
    const float* fc2c_W = (const float*)d_in[24];
    const float* fc2c_b = (const float*)d_in[25];
    const float* fc1v_W = (const float*)d_in[26];
    const float* fc1v_b = (const float*)d_in[27];
    const float* fc2v_W = (const float*)d_in[28];
    const float* fc2v_b = (const float*)d_in[29];
    const float* hW1 = (const float*)d_in[30];
    const float* hb1 = (const float*)d_in[31];
    const float* hW2 = (const float*)d_in[32];
    const float* hb2 = (const float*)d_in[33];
    const float* hW3 = (const float*)d_in[34];
    const float* hb3 = (const float*)d_in[35];
    float* out = (float*)d_out;

    char* p = (char*)d_ws;
    auto alloc = [&](size_t bytes) { char* ret = p; p += bytes; return ret; };
    float* ctx32 = (float*)alloc(16777216);
    float* val32 = (float*)alloc(16777216);
    bf16*  ob16c = (bf16*)alloc(8388608);
    bf16*  ob16v = (bf16*)alloc(8388608);
    bf16*  ctx16 = (bf16*)alloc(8388608);
    bf16*  val16 = (bf16*)alloc(8388608);
    bf16*  qk16  = (bf16*)alloc(16777216);   // A: [8192][1024]
    bf16*  v16   = (bf16*)alloc(8388608);    // B: [8192][512]
    bf16*  vt16  = (bf16*)alloc(8388608);    // C: [(b*8+h)*64+d][1024]
    bf16*  att16 = (bf16*)alloc(8388608);    // D
    bf16*  mid16c = (bf16*)alloc(33554432);  // [8192][2048]
    bf16*  qkT   = (bf16*)alloc(4194304);    // [4][1024][512]
    bf16*  vT    = (bf16*)alloc(2097152);    // [4][512][512]
    bf16*  oT    = (bf16*)alloc(2097152);
    bf16*  fc1cT = (bf16*)alloc(8388608);    // [4][2048][512]
    bf16*  fc2cT = (bf16*)alloc(8388608);    // [4][512][2048]
    bf16*  fc1vT = (bf16*)alloc(8388608);
    bf16*  fc2vT = (bf16*)alloc(8388608);
    bf16*  hW1T  = (bf16*)alloc(6291456);    // [2048][1536]
    bf16*  hW2T  = (bf16*)alloc(1048576);    // [256][2048]
    // aliases (liveness-checked):
    bf16*  mid16v = qk16;                    // A+B+C = exactly 33.5 MB, dead during FFN
    bf16*  feat16 = qk16;                    // A+B = exactly 8192*1536*2, post-loop
    float* h2     = (float*)vt16;            // C = exactly 8192*256*4, post-loop

    const dim3 tb(32, 8);
    transpose_kernel<<<dim3(16, 16, 4), tb, 0, stream>>>(Wq, qkT,          512, 512, 262144, 524288);
    transpose_kernel<<<dim3(16, 16, 4), tb, 0, stream>>>(Wk, qkT + 262144, 512, 512, 262144, 524288);
    transpose_kernel<<<dim3(16, 16, 4), tb, 0, stream>>>(Wv, vT, 512, 512, 262144, 262144);
    transpose_kernel<<<dim3(16, 16, 4), tb, 0, stream>>>(Wo, oT, 512, 512, 262144, 262144);
    transpose_kernel<<<dim3(64, 16, 4), tb, 0, stream>>>(fc1c_W, fc1cT, 512, 2048, 1048576, 1048576);
    transpose_kernel<<<dim3(16, 64, 4), tb, 0, stream>>>(fc2c_W, fc2cT, 2048, 512, 1048576, 1048576);
    transpose_kernel<<<dim3(64, 16, 4), tb, 0, stream>>>(fc1v_W, fc1vT, 512, 2048, 1048576, 1048576);
    transpose_kernel<<<dim3(16, 64, 4), tb, 0, stream>>>(fc2v_W, fc2vT, 2048, 512, 1048576, 1048576);
    transpose_kernel<<<dim3(64, 48, 1), tb, 0, stream>>>(hW1, hW1T, 1536, 2048, 0, 0);
    transpose_kernel<<<dim3(8, 64, 1),  tb, 0, stream>>>(hW2, hW2T, 2048, 256, 0, 0);

    embed_kernel<<<TOK, 256, 0, stream>>>(q, r, ctx_emb, val_emb, pos_emb,
                                          ctx32, val32, ctx16, val16);

    for (int i = 0; i < NBLK; ++i) {
        mfma_gemm<128, true><<<dim3(8, 64), 256, 0, stream>>>(
            (const ushort*)ctx16, (const ushort*)(qkT + (size_t)i * 524288),
            bq + i * DM, bk + i * DM, 512, qk16, 1024, 512, 0,
            nullptr, nullptr, nullptr, nullptr);
        mfma_gemm<64, true><<<dim3(8, 64), 256, 0, stream>>>(
            (const ushort*)val16, (const ushort*)(vT + (size_t)i * 262144),
            bv + i * DM, nullptr, 1 << 30, v16, 512, 512, 0,
            nullptr, nullptr, nullptr, nullptr);
        vtrans_kernel<<<dim3(16, 64), 256, 0, stream>>>(v16, vt16);
        attn_kernel<<<dim3(16, 64), 256, 0, stream>>>(qk16, vt16, att16);
        mfma_gemm<64, true><<<dim3(8, 64), 256, 0, stream>>>(
            (const ushort*)att16, (const ushort*)(oT + (size_t)i * 262144),
            bo + i * DM, nullptr, 1 << 30, ob16c, 512, 512, 0,
            nullptr, nullptr, nullptr, nullptr);
        lnp_kernel<<<dim3(TOK, 2), 256, 0, stream>>>(
            ctx32, ob16c, ln1c_s + i * DM, ln1c_b + i * DM, ctx32, ctx16,
            val32, ob16c, ln1v_s + i * DM, ln1v_b + i * DM, val32, val16);
        mfma_gemm<128, true><<<dim3(16, 64, 2), 256, 0, stream>>>(
            (const ushort*)ctx16, (const ushort*)(fc1cT + (size_t)i * 1048576),
            fc1c_b + i * DFFN, nullptr, 1 << 30, mid16c, 2048, 512, 1,
            (const ushort*)val16, (const ushort*)(fc1vT + (size_t)i * 1048576),
            fc1v_b + i * DFFN, mid16v);
        mfma_gemm<64, true><<<dim3(8, 64, 2), 256, 0, stream>>>(
            (const ushort*)mid16c, (const ushort*)(fc2cT + (size_t)i * 1048576),
            fc2c_b + i * DM, nullptr, 1 << 30, ob16c, 512, 2048, 0,
            (const ushort*)mid16v, (const ushort*)(fc2vT + (size_t)i * 1048576),
            fc2v_b + i * DM, ob16v);
        lnp_kernel<<<dim3(TOK, 2), 256, 0, stream>>>(
            ctx32, ob16c, ln2c_s + i * DM, ln2c_b + i * DM, ctx32, ctx16,
            val32, ob16v, ln2v_s + i * DM, ln2v_b + i * DM, val32, val16);
    }

    gather_kernel<<<TOK, 256, 0, stream>>>(ctx16, val16, skill_emb, q, feat16);
    mfma_gemm<128, true><<<dim3(16, 64), 256, 0, stream>>>(
        (const ushort*)feat16, (const ushort*)hW1T, hb1, nullptr, 1 << 30, mid16c, 2048, 1536, 1,
        nullptr, nullptr, nullptr, nullptr);
    mfma_gemm<64, false><<<dim3(4, 64), 256, 0, stream>>>(
        (const ushort*)mid16c, (const ushort*)hW2T, hb2, nullptr, 1 << 30, h2, 256, 2048, 1,
        nullptr, nullptr, nullptr, nullptr);
    logits_kernel<<<TOK, 256, 0, stream>>>(h2, hW3, hb3, out);
}

// Round 4
// 1275.240 us; speedup vs baseline: 6.0248x; 1.1892x over previous
//
#include <hip/hip_runtime.h>
#include <hip/hip_bf16.h>
#include <math.h>

#define TOK 8192   // B*L
#define DM 512
#define NH 8
#define DKH 64
#define DFFN 2048
#define SEQ 1024
#define NBLK 4
#define NUMC 1000

typedef __attribute__((ext_vector_type(8))) short bf16x8;
typedef __attribute__((ext_vector_type(4))) float f32x4;
typedef __hip_bfloat16 bf16;

__device__ __forceinline__ void gload_lds16(const ushort* g, ushort* l) {
    __builtin_amdgcn_global_load_lds(
        (const __attribute__((address_space(1))) void*)g,
        (__attribute__((address_space(3))) void*)l, 16, 0, 0);
}

// ---------------------------------------------------------------- embed
__global__ __launch_bounds__(256) void embed_kernel(
    const int* __restrict__ q, const int* __restrict__ r,
    const float* __restrict__ ctx_emb, const float* __restrict__ val_emb,
    const float* __restrict__ pos_emb,
    float* __restrict__ ctx32, float* __restrict__ val32,
    bf16* __restrict__ ctx16, bf16* __restrict__ val16)
{
    const int t = blockIdx.x;
    const int inter = q[t] + NUMC * r[t];
    const int l = t & (SEQ - 1);
    const float* ce = ctx_emb + (size_t)inter * DM;
    const float* ve = val_emb + (size_t)inter * DM;
    const float* pe = pos_emb + (size_t)l * DM;
    const size_t o = (size_t)t * DM;
    for (int d = threadIdx.x; d < DM; d += 256) {
        float p = pe[d];
        float c = ce[d] + p;
        float v = ve[d] + p;
        ctx32[o + d] = c; val32[o + d] = v;
        ctx16[o + d] = __float2bfloat16(c);
        val16[o + d] = __float2bfloat16(v);
    }
}

// ---------------------------------------------------------------- transpose+cvt (weights)
// dst[n][k] = bf16(src[k][n]); src [K][N] fp32, dst row stride K.
__global__ __launch_bounds__(256) void transpose_kernel(
    const float* __restrict__ src, bf16* __restrict__ dst,
    int K, int N, long sb, long db)
{
    __shared__ float t[32][33];
    src += (long)blockIdx.z * sb;
    dst += (long)blockIdx.z * db;
    const int n0 = blockIdx.x * 32;
    const int k0 = blockIdx.y * 32;
    const int tx = threadIdx.x;            // 0..31
    const int ty = threadIdx.y;            // 0..7
    for (int i = ty; i < 32; i += 8) t[i][tx] = src[(size_t)(k0 + i) * N + n0 + tx];
    __syncthreads();
    for (int i = ty; i < 32; i += 8)
        dst[(size_t)(n0 + i) * K + k0 + tx] = __float2bfloat16(t[tx][i]);
}

// ---------------------------------------------------------------- V transpose (bf16)
// in: [8192][512] = [b*1024+key][h*64+d]  ->  out: [(b*8+h)*64+d][1024 keys]
__global__ __launch_bounds__(256) void vtrans_kernel(
    const bf16* __restrict__ in, bf16* __restrict__ outp)
{
    __shared__ ushort T[64 * 66];
    const int ktile = blockIdx.x;   // 16
    const int bh = blockIdx.y;      // 64
    const int b = bh >> 3, h = bh & 7;
    const int t = threadIdx.x;
    const int key = t >> 2, c0 = (t & 3) * 16;
    const bf16* src = in + (size_t)(b * SEQ + ktile * 64 + key) * 512 + h * 64 + c0;
    *(bf16x8*)&T[key * 66 + c0] = *(const bf16x8*)src;
    *(bf16x8*)&T[key * 66 + c0 + 8] = *(const bf16x8*)(src + 8);
    __syncthreads();
    const int d = t >> 2, k0 = (t & 3) * 16;
    bf16x8 w0, w1;
#pragma unroll
    for (int j = 0; j < 8; ++j) w0[j] = ((short*)T)[(k0 + j) * 66 + d];
#pragma unroll
    for (int j = 0; j < 8; ++j) w1[j] = ((short*)T)[(k0 + 8 + j) * 66 + d];
    bf16* dst = outp + (size_t)(bh * 64 + d) * SEQ + ktile * 64 + k0;
    *(bf16x8*)dst = w0;
    *(bf16x8*)(dst + 8) = w1;
}

// ---------------------------------------------------------------- MFMA GEMM
// C[M,N] = A[M,K](bf16) @ Bt[N,K](bf16)^T + bias, opt ReLU.
// 128 x BN tile, BK=32, 256 thr (4 waves), global_load_lds width-16 staging.
// XCD swizzle: all n-tiles of one m-tile -> same XCD (lin&7), consecutive, so
// the A-slab stays L2-resident across its n-blocks. Requires gridDim.x*gridDim.y % 8 == 0.
// blockIdx.z==1 selects the second (A1,Bt1,bias1_1,Cv1) problem (batched FFN).
template<int BN, bool OUTBF16>
__global__ __launch_bounds__(256, 2) void mfma_gemm(
    const ushort* __restrict__ A, const ushort* __restrict__ Bt,
    const float* __restrict__ bias1, const float* __restrict__ bias2, int split,
    void* __restrict__ Cv, int N, int K, int relu,
    const ushort* __restrict__ A1, const ushort* __restrict__ Bt1,
    const float* __restrict__ bias1_1, void* __restrict__ Cv1)
{
    if (blockIdx.z) { A = A1; Bt = Bt1; bias1 = bias1_1; Cv = Cv1; }
    constexpr int MI = (BN == 128) ? 4 : 2;
    __shared__ ushort As[128 * 32];
    __shared__ ushort Bs[BN * 32];
    const int tid = threadIdx.x;
    const int wave = tid >> 6;
    const int lane = tid & 63;
    const int ln = lane & 15;
    const int kq = lane >> 4;
    // XCD-locality swizzle
    const int nx = gridDim.x;
    const int lin = blockIdx.x + nx * blockIdx.y;
    const int loc = lin >> 3;
    const int mdiv = loc / nx;
    const int bm = ((lin & 7) + 8 * mdiv) * 128;
    const int bn = (loc - mdiv * nx) * BN;
    const int wr = (BN == 128) ? (wave >> 1) * 64 : wave * 32;
    const int wc = (BN == 128) ? (wave & 1) * 64 : 0;

    const int srow = tid >> 2;
    const int scol = (tid & 3) * 8;
    const ushort* Ag0 = A + (size_t)(bm + srow) * K + scol;
    const ushort* Ag1 = A + (size_t)(bm + 64 + srow) * K + scol;
    const ushort* Bg0 = Bt + (size_t)(bn + srow) * K + scol;
    const ushort* Bg1 = (BN == 128) ? (Bt + (size_t)(bn + 64 + srow) * K + scol) : nullptr;
    ushort* AsW0 = As + wave * 512;
    ushort* AsW1 = As + 2048 + wave * 512;
    ushort* BsW0 = Bs + wave * 512;
    ushort* BsW1 = Bs + 2048 + wave * 512;

    f32x4 acc[MI][4];
#pragma unroll
    for (int i = 0; i < MI; ++i)
#pragma unroll
        for (int j = 0; j < 4; ++j) acc[i][j] = (f32x4){0.f, 0.f, 0.f, 0.f};

    for (int k0 = 0; k0 < K; k0 += 32) {
        __syncthreads();
        gload_lds16(Ag0 + k0, AsW0);
        gload_lds16(Ag1 + k0, AsW1);
        gload_lds16(Bg0 + k0, BsW0);
        if (BN == 128) gload_lds16(Bg1 + k0, BsW1);
        __syncthreads();
        bf16x8 bfr[4];
#pragma unroll
        for (int j = 0; j < 4; ++j)
            bfr[j] = *(const bf16x8*)&Bs[(wc + j * 16 + ln) * 32 + kq * 8];
#pragma unroll
        for (int i = 0; i < MI; ++i) {
            const bf16x8 af = *(const bf16x8*)&As[(wr + i * 16 + ln) * 32 + kq * 8];
#pragma unroll
            for (int j = 0; j < 4; ++j)
                acc[i][j] = __builtin_amdgcn_mfma_f32_16x16x32_bf16(af, bfr[j], acc[i][j], 0, 0, 0);
        }
    }

#pragma unroll
    for (int i = 0; i < MI; ++i) {
        const int rowb = bm + wr + i * 16 + kq * 4;
#pragma unroll
        for (int j = 0; j < 4; ++j) {
            const int colg = bn + wc + j * 16 + ln;
            const float bv = (colg < split) ? bias1[colg] : bias2[colg - split];
#pragma unroll
            for (int rr = 0; rr < 4; ++rr) {
                float v = acc[i][j][rr] + bv;
                if (relu) v = fmaxf(v, 0.f);
                if (OUTBF16)
                    ((bf16*)Cv)[(size_t)(rowb + rr) * N + colg] = __float2bfloat16(v);
                else
                    ((float*)Cv)[(size_t)(rowb + rr) * N + colg] = v;
            }
        }
    }
}

// ---------------------------------------------------------------- MFMA flash attention
// One block per (qt, b*8+h). 4 waves x 16 q-rows, j-tiles of 64 keys.
// QK: [t][1024] (Q cols h*64, K cols 512+h*64); Vt: [(b*8+h)*64+d][1024 keys].
// XCD swizzle: bh%8 -> XCD so each XCD's K/V working set (8 heads x 256KB) fits L2.
__global__ __launch_bounds__(256) void attn_kernel(
    const bf16* __restrict__ QK, const bf16* __restrict__ Vt,
    bf16* __restrict__ Og)
{
    __shared__ ushort Qs[64 * 68];
    __shared__ ushort Ks[64 * 68];
    __shared__ ushort Vs[64 * 68];      // [dim][key] for current j-tile
    __shared__ ushort Ps[4 * 16 * 68];  // per-wave P (16 q-rows x 64 keys)

    const int tid = threadIdx.x;
    const int wave = tid >> 6, lane = tid & 63;
    const int ln = lane & 15, kq = lane >> 4;
    const int lin = blockIdx.x + 16 * blockIdx.y;
    const int loc = lin >> 3;
    const int qt = loc & 15;
    const int bh = (lin & 7) + 8 * (loc >> 4);
    const int b = bh >> 3, h = bh & 7;

    const int srow = tid >> 2;
    const int sc0 = (tid & 3) * 16;
    {
        const bf16* src = QK + (size_t)(b * SEQ + qt * 64 + srow) * 1024 + h * 64 + sc0;
        *(bf16x8*)&Qs[srow * 68 + sc0] = *(const bf16x8*)src;
        *(bf16x8*)&Qs[srow * 68 + sc0 + 8] = *(const bf16x8*)(src + 8);
    }

    float m2[4], lsum[4];
    f32x4 oacc[4];
#pragma unroll
    for (int r = 0; r < 4; ++r) { m2[r] = -INFINITY; lsum[r] = 0.f; oacc[r] = (f32x4){0.f,0.f,0.f,0.f}; }
    const float sc2 = 0.125f * 1.4426950408889634f;   // 1/sqrt(64) * log2(e)

    for (int kt = 0; kt <= qt; ++kt) {
        __syncthreads();   // prev-iter LDS reads (and initial Q write) complete
        {
            const bf16* ksrc = QK + (size_t)(b * SEQ + kt * 64 + srow) * 1024 + 512 + h * 64 + sc0;
            *(bf16x8*)&Ks[srow * 68 + sc0] = *(const bf16x8*)ksrc;
            *(bf16x8*)&Ks[srow * 68 + sc0 + 8] = *(const bf16x8*)(ksrc + 8);
            const bf16* vsrc = Vt + (size_t)(bh * 64 + srow) * SEQ + kt * 64 + sc0;
            *(bf16x8*)&Vs[srow * 68 + sc0] = *(const bf16x8*)vsrc;
            *(bf16x8*)&Vs[srow * 68 + sc0 + 8] = *(const bf16x8*)(vsrc + 8);
        }
        __syncthreads();

        // S = Q K^T : per wave 16x64, 4 col-tiles x 2 k-halves
        const bf16x8 aq0 = *(const bf16x8*)&Qs[(wave * 16 + ln) * 68 + kq * 8];
        const bf16x8 aq1 = *(const bf16x8*)&Qs[(wave * 16 + ln) * 68 + 32 + kq * 8];
        f32x4 s[4];
#pragma unroll
        for (int c = 0; c < 4; ++c) {
            const bf16x8 bk0 = *(const bf16x8*)&Ks[(c * 16 + ln) * 68 + kq * 8];
            const bf16x8 bk1 = *(const bf16x8*)&Ks[(c * 16 + ln) * 68 + 32 + kq * 8];
            s[c] = (f32x4){0.f, 0.f, 0.f, 0.f};
            s[c] = __builtin_amdgcn_mfma_f32_16x16x32_bf16(aq0, bk0, s[c], 0, 0, 0);
            s[c] = __builtin_amdgcn_mfma_f32_16x16x32_bf16(aq1, bk1, s[c], 0, 0, 0);
        }
        // scale into log2 domain (+ causal mask on the diagonal tile)
        if (kt == qt) {
#pragma unroll
            for (int c = 0; c < 4; ++c)
#pragma unroll
                for (int r = 0; r < 4; ++r) {
                    const int qg = wave * 16 + kq * 4 + r;
                    const int jg = c * 16 + ln;
                    s[c][r] = (jg <= qg) ? s[c][r] * sc2 : -INFINITY;
                }
        } else {
#pragma unroll
            for (int c = 0; c < 4; ++c)
#pragma unroll
                for (int r = 0; r < 4; ++r) s[c][r] *= sc2;
        }
        // online softmax: row reductions via shfl_xor over the 16-lane col group
        float alpha[4];
#pragma unroll
        for (int r = 0; r < 4; ++r) {
            float v = fmaxf(fmaxf(s[0][r], s[1][r]), fmaxf(s[2][r], s[3][r]));
            v = fmaxf(v, __shfl_xor(v, 1));
            v = fmaxf(v, __shfl_xor(v, 2));
            v = fmaxf(v, __shfl_xor(v, 4));
            v = fmaxf(v, __shfl_xor(v, 8));
            const float mn = fmaxf(m2[r], v);
            alpha[r] = exp2f(m2[r] - mn);
            m2[r] = mn;
        }
        float rs[4] = {0.f, 0.f, 0.f, 0.f};
#pragma unroll
        for (int c = 0; c < 4; ++c)
#pragma unroll
            for (int r = 0; r < 4; ++r) {
                const float pv = exp2f(s[c][r] - m2[r]);
                rs[r] += pv;
                // C-layout -> LDS (wave-private region, stride-68: conflict-free)
                *(bf16*)&Ps[wave * 1088 + (kq * 4 + r) * 68 + c * 16 + ln] = __float2bfloat16(pv);
            }
#pragma unroll
        for (int r = 0; r < 4; ++r) {
            float v = rs[r];
            v += __shfl_xor(v, 1);
            v += __shfl_xor(v, 2);
            v += __shfl_xor(v, 4);
            v += __shfl_xor(v, 8);
            lsum[r] = lsum[r] * alpha[r] + v;
        }
#pragma unroll
        for (int c2 = 0; c2 < 4; ++c2)
#pragma unroll
            for (int r = 0; r < 4; ++r) oacc[c2][r] *= alpha[r];
        // P V : P back from LDS in A-layout (same-wave RAW, lgkmcnt handled by compiler)
        const bf16x8 ap0 = *(const bf16x8*)&Ps[wave * 1088 + ln * 68 + kq * 8];
        const bf16x8 ap1 = *(const bf16x8*)&Ps[wave * 1088 + ln * 68 + 32 + kq * 8];
#pragma unroll
        for (int c2 = 0; c2 < 4; ++c2) {
            const bf16x8 bv0 = *(const bf16x8*)&Vs[(c2 * 16 + ln) * 68 + kq * 8];
            const bf16x8 bv1 = *(const bf16x8*)&Vs[(c2 * 16 + ln) * 68 + 32 + kq * 8];
            oacc[c2] = __builtin_amdgcn_mfma_f32_16x16x32_bf16(ap0, bv0, oacc[c2], 0, 0, 0);
            oacc[c2] = __builtin_amdgcn_mfma_f32_16x16x32_bf16(ap1, bv1, oacc[c2], 0, 0, 0);
        }
    }
    float inv[4];
#pragma unroll
    for (int r = 0; r < 4; ++r) inv[r] = 1.f / lsum[r];
#pragma unroll
    for (int c2 = 0; c2 < 4; ++c2)
#pragma unroll
        for (int r = 0; r < 4; ++r)
            Og[(size_t)(b * SEQ + qt * 64 + wave * 16 + kq * 4 + r) * 512 + h * 64 + c2 * 16 + ln]
                = __float2bfloat16(oacc[c2][r] * inv[r]);
}

// ---------------------------------------------------------------- layernorm pair
// out = LN(x + res) * s + b ; blockIdx.y picks problem 0/1.
__global__ __launch_bounds__(256) void lnp_kernel(
    const float* __restrict__ x0, const bf16* __restrict__ r0, const float* __restrict__ s0,
    const float* __restrict__ b0, float* __restrict__ of0, bf16* __restrict__ oh0,
    const float* __restrict__ x1, const bf16* __restrict__ r1, const float* __restrict__ s1,
    const float* __restrict__ b1, float* __restrict__ of1, bf16* __restrict__ oh1)
{
    const float* x = x0; const bf16* res = r0; const float* s = s0; const float* bb = b0;
    float* of = of0; bf16* oh = oh0;
    if (blockIdx.y) { x = x1; res = r1; s = s1; bb = b1; of = of1; oh = oh1; }
    __shared__ float w1[4], w2[4];
    const size_t o = (size_t)blockIdx.x * DM;
    const int i0 = threadIdx.x, i1 = threadIdx.x + 256;
    const float v0 = x[o + i0] + __bfloat162float(res[o + i0]);
    const float v1 = x[o + i1] + __bfloat162float(res[o + i1]);
    float sum = v0 + v1;
#pragma unroll
    for (int off = 32; off; off >>= 1) sum += __shfl_down(sum, off);
    if ((threadIdx.x & 63) == 0) w1[threadIdx.x >> 6] = sum;
    __syncthreads();
    const float mu = (w1[0] + w1[1] + w1[2] + w1[3]) * (1.f / DM);
    const float d0 = v0 - mu, d1 = v1 - mu;
    float vs = d0 * d0 + d1 * d1;
#pragma unroll
    for (int off = 32; off; off >>= 1) vs += __shfl_down(vs, off);
    if ((threadIdx.x & 63) == 0) w2[threadIdx.x >> 6] = vs;
    __syncthreads();
    const float rstd = rsqrtf((w2[0] + w2[1] + w2[2] + w2[3]) * (1.f / DM) + 1e-5f);
    const float o0 = d0 * rstd * s[i0] + bb[i0];
    const float o1 = d1 * rstd * s[i1] + bb[i1];
    of[o + i0] = o0; of[o + i1] = o1;
    oh[o + i0] = __float2bfloat16(o0);
    oh[o + i1] = __float2bfloat16(o1);
}

// ---------------------------------------------------------------- head gather
__global__ __launch_bounds__(256) void gather_kernel(
    const bf16* __restrict__ ctx16, const bf16* __restrict__ val16,
    const float* __restrict__ skill, const int* __restrict__ q,
    bf16* __restrict__ feat)
{
    const int t = blockIdx.x;
    const float* sp = skill + (size_t)q[t] * DM;
    const bf16* cp = ctx16 + (size_t)t * DM;
    const bf16* vp = val16 + (size_t)t * DM;
    bf16* fp = feat + (size_t)t * (3 * DM);
    for (int d = threadIdx.x; d < DM; d += 256) {
        fp[d] = cp[d];
        fp[DM + d] = vp[d];
        fp[2 * DM + d] = __float2bfloat16(sp[d]);
    }
}

// ---------------------------------------------------------------- logits
__global__ __launch_bounds__(256) void logits_kernel(
    const float* __restrict__ h2, const float* __restrict__ w,
    const float* __restrict__ bptr, float* __restrict__ out)
{
    __shared__ float w1[4];
    const int t = blockIdx.x;
    float sum = h2[(size_t)t * 256 + threadIdx.x] * w[threadIdx.x];
#pragma unroll
    for (int off = 32; off; off >>= 1) sum += __shfl_down(sum, off);
    if ((threadIdx.x & 63) == 0) w1[threadIdx.x >> 6] = sum;
    __syncthreads();
    if (threadIdx.x == 0) {
        const float logit = w1[0] + w1[1] + w1[2] + w1[3] + bptr[0];
        out[t] = 1.f / (1.f + __expf(-logit));
    }
}

// ---------------------------------------------------------------- launch
extern "C" void kernel_launch(void* const* d_in, const int* in_sizes, int n_in,
                              void* d_out, int out_size, void* d_ws, size_t ws_size,
                              hipStream_t stream)
{
    const int*   q         = (const int*)d_in[0];
    const int*   r         = (const int*)d_in[1];
    const float* ctx_emb   = (const float*)d_in[2];
    const float* val_emb   = (const float*)d_in[3];
    const float* skill_emb = (const float*)d_in[4];
    const float* pos_emb   = (const float*)d_in[5];
    const float* Wq = (const float*)d_in[6];
    const float* bq = (const float*)d_in[7];
    const float* Wk = (const float*)d_in[8];
    const float* bk = (const float*)d_in[9];
    const float* Wv = (const float*)d_in[10];
    const float* bv = (const float*)d_in[11];
    const float* Wo = (const float*)d_in[12];
    const float* bo = (const float*)d_in[13];
    const float* ln1c_s = (const float*)d_in[14];
    const float* ln1c_b = (const float*)d_in[15];
    const float* ln1v_s = (const float*)d_in[16];
    const float* ln1v_b = (const float*)d_in[17];
    const float* ln2c_s = (const float*)d_in[18];
    const float* ln2c_b = (const float*)d_in[19];
    const float* ln2v_s = (const float*)d_in[20];
    const float* ln2v_b = (const float*)d_in[21];
    const float* fc1c_W = (const float*)d_in[22];
    const float* fc1c_b = (const float*)d_in[23];
    const float* fc2c_W = (const float*)d_in[24];
    const float* fc2c_b = (const float*)d_in[25];
    const float* fc1v_W = (const float*)d_in[26];
    const float* fc1v_b = (const float*)d_in[27];
    const float* fc2v_W = (const float*)d_in[28];
    const float* fc2v_b = (const float*)d_in[29];
    const float* hW1 = (const float*)d_in[30];
    const float* hb1 = (const float*)d_in[31];
    const float* hW2 = (const float*)d_in[32];
    const float* hb2 = (const float*)d_in[33];
    const float* hW3 = (const float*)d_in[34];
    const float* hb3 = (const float*)d_in[35];
    float* out = (float*)d_out;

    char* p = (char*)d_ws;
    auto alloc = [&](size_t bytes) { char* ret = p; p += bytes; return ret; };
    float* ctx32 = (float*)alloc(16777216);
    float* val32 = (float*)alloc(16777216);
    bf16*  ob16c = (bf16*)alloc(8388608);
    bf16*  ob16v = (bf16*)alloc(8388608);
    bf16*  ctx16 = (bf16*)alloc(8388608);
    bf16*  val16 = (bf16*)alloc(8388608);
    bf16*  qk16  = (bf16*)alloc(16777216);   // A: [8192][1024]
    bf16*  v16   = (bf16*)alloc(8388608);    // B: [8192][512]
    bf16*  vt16  = (bf16*)alloc(8388608);    // C: [(b*8+h)*64+d][1024]
    bf16*  att16 = (bf16*)alloc(8388608);    // D
    bf16*  mid16c = (bf16*)alloc(33554432);  // [8192][2048]
    bf16*  qkT   = (bf16*)alloc(4194304);    // [4][1024][512]
    bf16*  vT    = (bf16*)alloc(2097152);    // [4][512][512]
    bf16*  oT    = (bf16*)alloc(2097152);
    bf16*  fc1cT = (bf16*)alloc(8388608);    // [4][2048][512]
    bf16*  fc2cT = (bf16*)alloc(8388608);    // [4][512][2048]
    bf16*  fc1vT = (bf16*)alloc(8388608);
    bf16*  fc2vT = (bf16*)alloc(8388608);
    bf16*  hW1T  = (bf16*)alloc(6291456);    // [2048][1536]
    bf16*  hW2T  = (bf16*)alloc(1048576);    // [256][2048]
    // aliases (liveness-checked):
    bf16*  mid16v = qk16;                    // A+B+C = exactly 33.5 MB, dead during FFN
    bf16*  feat16 = qk16;                    // A+B = exactly 8192*1536*2, post-loop
    float* h2     = (float*)vt16;            // C = exactly 8192*256*4, post-loop

    const dim3 tb(32, 8);
    transpose_kernel<<<dim3(16, 16, 4), tb, 0, stream>>>(Wq, qkT,          512, 512, 262144, 524288);
    transpose_kernel<<<dim3(16, 16, 4), tb, 0, stream>>>(Wk, qkT + 262144, 512, 512, 262144, 524288);
    transpose_kernel<<<dim3(16, 16, 4), tb, 0, stream>>>(Wv, vT, 512, 512, 262144, 262144);
    transpose_kernel<<<dim3(16, 16, 4), tb, 0, stream>>>(Wo, oT, 512, 512, 262144, 262144);
    transpose_kernel<<<dim3(64, 16, 4), tb, 0, stream>>>(fc1c_W, fc1cT, 512, 2048, 1048576, 1048576);
    transpose_kernel<<<dim3(16, 64, 4), tb, 0, stream>>>(fc2c_W, fc2cT, 2048, 512, 1048576, 1048576);
    transpose_kernel<<<dim3(64, 16, 4), tb, 0, stream>>>(fc1v_W, fc1vT, 512, 2048, 1048576, 1048576);
    transpose_kernel<<<dim3(16, 64, 4), tb, 0, stream>>>(fc2v_W, fc2vT, 2048, 512, 1048576, 1048576);
    transpose_kernel<<<dim3(64, 48, 1), tb, 0, stream>>>(hW1, hW1T, 1536, 2048, 0, 0);
    transpose_kernel<<<dim3(8, 64, 1),  tb, 0, stream>>>(hW2, hW2T, 2048, 256, 0, 0);

    embed_kernel<<<TOK, 256, 0, stream>>>(q, r, ctx_emb, val_emb, pos_emb,
                                          ctx32, val32, ctx16, val16);

    for (int i = 0; i < NBLK; ++i) {
        mfma_gemm<128, true><<<dim3(8, 64), 256, 0, stream>>>(
            (const ushort*)ctx16, (const ushort*)(qkT + (size_t)i * 524288),
            bq + i * DM, bk + i * DM, 512, qk16, 1024, 512, 0,
            nullptr, nullptr, nullptr, nullptr);
        mfma_gemm<64, true><<<dim3(8, 64), 256, 0, stream>>>(
            (const ushort*)val16, (const ushort*)(vT + (size_t)i * 262144),
            bv + i * DM, nullptr, 1 << 30, v16, 512, 512, 0,
            nullptr, nullptr, nullptr, nullptr);
        vtrans_kernel<<<dim3(16, 64), 256, 0, stream>>>(v16, vt16);
        attn_kernel<<<dim3(16, 64), 256, 0, stream>>>(qk16, vt16, att16);
        mfma_gemm<64, true><<<dim3(8, 64), 256, 0, stream>>>(
            (const ushort*)att16, (const ushort*)(oT + (size_t)i * 262144),
            bo + i * DM, nullptr, 1 << 30, ob16c, 512, 512, 0,
            nullptr, nullptr, nullptr, nullptr);
        lnp_kernel<<<dim3(TOK, 2), 256, 0, stream>>>(
            ctx32, ob16c, ln1c_s + i * DM, ln1c_b + i * DM, ctx32, ctx16,
            val32, ob16c, ln1v_s + i * DM, ln1v_b + i * DM, val32, val16);
        mfma_gemm<128, true><<<dim3(16, 64, 2), 256, 0, stream>>>(
            (const ushort*)ctx16, (const ushort*)(fc1cT + (size_t)i * 1048576),
            fc1c_b + i * DFFN, nullptr, 1 << 30, mid16c, 2048, 512, 1,
            (const ushort*)val16, (const ushort*)(fc1vT + (size_t)i * 1048576),
            fc1v_b + i * DFFN, mid16v);
        mfma_gemm<128, true><<<dim3(4, 64, 2), 256, 0, stream>>>(
            (const ushort*)mid16c, (const ushort*)(fc2cT + (size_t)i * 1048576),
            fc2c_b + i * DM, nullptr, 1 << 30, ob16c, 512, 2048, 0,
            (const ushort*)mid16v, (const ushort*)(fc2vT + (size_t)i * 1048576),
            fc2v_b + i * DM, ob16v);
        lnp_kernel<<<dim3(TOK, 2), 256, 0, stream>>>(
            ctx32, ob16c, ln2c_s + i * DM, ln2c_b + i * DM, ctx32, ctx16,
            val32, ob16v, ln2v_s + i * DM, ln2v_b + i * DM, val32, val16);
    }

    gather_kernel<<<TOK, 256, 0, stream>>>(ctx16, val16, skill_emb, q, feat16);
    mfma_gemm<128, true><<<dim3(16, 64), 256, 0, stream>>>(
        (const ushort*)feat16, (const ushort*)hW1T, hb1, nullptr, 1 << 30, mid16c, 2048, 1536, 1,
        nullptr, nullptr, nullptr, nullptr);
    mfma_gemm<64, false><<<dim3(4, 64), 256, 0, stream>>>(
        (const ushort*)mid16c, (const ushort*)hW2T, hb2, nullptr, 1 << 30, h2, 256, 2048, 1,
        nullptr, nullptr, nullptr, nullptr);
    logits_kernel<<<TOK, 256, 0, stream>>>(h2, hW3, hb3, out);
}

// Round 5
// 1150.743 us; speedup vs baseline: 6.6766x; 1.1082x over previous
//
#include <hip/hip_runtime.h>
#include <hip/hip_bf16.h>
#include <math.h>

#define TOK 8192   // B*L
#define DM 512
#define NH 8
#define DKH 64
#define DFFN 2048
#define SEQ 1024
#define NBLK 4
#define NUMC 1000

typedef __attribute__((ext_vector_type(8))) short bf16x8;
typedef __attribute__((ext_vector_type(4))) float f32x4;
typedef __attribute__((ext_vector_type(4))) ushort u16x4;
typedef __hip_bfloat16 bf16;

__device__ __forceinline__ void gload_lds16(const ushort* g, ushort* l) {
    __builtin_amdgcn_global_load_lds(
        (const __attribute__((address_space(1))) void*)g,
        (__attribute__((address_space(3))) void*)l, 16, 0, 0);
}

// ---------------------------------------------------------------- embed
__global__ __launch_bounds__(256) void embed_kernel(
    const int* __restrict__ q, const int* __restrict__ r,
    const float* __restrict__ ctx_emb, const float* __restrict__ val_emb,
    const float* __restrict__ pos_emb,
    float* __restrict__ ctx32, float* __restrict__ val32,
    bf16* __restrict__ ctx16, bf16* __restrict__ val16)
{
    const int t = blockIdx.x;
    const int inter = q[t] + NUMC * r[t];
    const int l = t & (SEQ - 1);
    const float* ce = ctx_emb + (size_t)inter * DM;
    const float* ve = val_emb + (size_t)inter * DM;
    const float* pe = pos_emb + (size_t)l * DM;
    const size_t o = (size_t)t * DM;
    for (int d = threadIdx.x; d < DM; d += 256) {
        float p = pe[d];
        float c = ce[d] + p;
        float v = ve[d] + p;
        ctx32[o + d] = c; val32[o + d] = v;
        ctx16[o + d] = __float2bfloat16(c);
        val16[o + d] = __float2bfloat16(v);
    }
}

// ---------------------------------------------------------------- transpose+cvt (weights)
// dst[n][k] = bf16(src[k][n]); src [K][N] fp32, dst row stride K.
__global__ __launch_bounds__(256) void transpose_kernel(
    const float* __restrict__ src, bf16* __restrict__ dst,
    int K, int N, long sb, long db)
{
    __shared__ float t[32][33];
    src += (long)blockIdx.z * sb;
    dst += (long)blockIdx.z * db;
    const int n0 = blockIdx.x * 32;
    const int k0 = blockIdx.y * 32;
    const int tx = threadIdx.x;            // 0..31
    const int ty = threadIdx.y;            // 0..7
    for (int i = ty; i < 32; i += 8) t[i][tx] = src[(size_t)(k0 + i) * N + n0 + tx];
    __syncthreads();
    for (int i = ty; i < 32; i += 8)
        dst[(size_t)(n0 + i) * K + k0 + tx] = __float2bfloat16(t[tx][i]);
}

// ---------------------------------------------------------------- MFMA GEMM
// C[M,N] = A[M,K](bf16) @ Bt[N,K](bf16)^T + bias, opt ReLU.
// 128 x BN tile, BK=64, 256 thr (4 waves), global_load_lds width-16 staging.
// XOR colblock swizzle: LDS[r][cb] = global[r][cb ^ (r&7)] (8-ushort blocks),
// folded into the *global* address so staging stays lane-contiguous; fragment
// reads then spread 8 blocks x 16B = all 32 banks (2-way = free).
// XCD swizzle: all n-tiles of one m-tile -> same XCD (lin&7), consecutive.
// vtmode: write C transposed into Vt[(row>>10)*512 + col][1024] (fuses vtrans).
// blockIdx.z==1 selects the second (A1,Bt1,bias1_1,Cv1) problem (batched FFN).
template<int BN, bool OUTBF16>
__global__ __launch_bounds__(256, 3) void mfma_gemm(
    const ushort* __restrict__ A, const ushort* __restrict__ Bt,
    const float* __restrict__ bias1, const float* __restrict__ bias2, int split,
    void* __restrict__ Cv, int N, int K, int relu, int vtmode,
    const ushort* __restrict__ A1, const ushort* __restrict__ Bt1,
    const float* __restrict__ bias1_1, void* __restrict__ Cv1)
{
    if (blockIdx.z) { A = A1; Bt = Bt1; bias1 = bias1_1; Cv = Cv1; }
    constexpr int MI = (BN == 128) ? 4 : 2;
    constexpr int BR = BN / 32;            // B staging rounds
    __shared__ ushort As[128 * 64];
    __shared__ ushort Bs[BN * 64];
    const int tid = threadIdx.x;
    const int wave = tid >> 6;
    const int lane = tid & 63;
    const int ln = lane & 15;
    const int kq = lane >> 4;
    // XCD-locality swizzle
    const int nx = gridDim.x;
    const int lin = blockIdx.x + nx * blockIdx.y;
    const int loc = lin >> 3;
    const int mdiv = loc / nx;
    const int bm = ((lin & 7) + 8 * mdiv) * 128;
    const int bn = (loc - mdiv * nx) * BN;
    const int wr = (BN == 128) ? (wave >> 1) * 64 : wave * 32;
    const int wc = (BN == 128) ? (wave & 1) * 64 : 0;

    // staging: thread t covers row 32p+(t>>3), LDS colblock t&7,
    // global colblock (t&7)^((t>>3)&7)  [32p doesn't affect row&7]
    const int trow = tid >> 3;             // 0..31
    const int gcb = (tid & 7) ^ (trow & 7);
    const ushort* Ab = A + (size_t)(bm + trow) * K + gcb * 8;
    const ushort* Bb = Bt + (size_t)(bn + trow) * K + gcb * 8;
    ushort* AsW = As + wave * 512;         // + p*2048; lane dest = base + lane*16B
    ushort* BsW = Bs + wave * 512;

    f32x4 acc[MI][4];
#pragma unroll
    for (int i = 0; i < MI; ++i)
#pragma unroll
        for (int j = 0; j < 4; ++j) acc[i][j] = (f32x4){0.f, 0.f, 0.f, 0.f};

    for (int k0 = 0; k0 < K; k0 += 64) {
        __syncthreads();
#pragma unroll
        for (int p = 0; p < 4; ++p)
            gload_lds16(Ab + (size_t)32 * p * K + k0, AsW + p * 2048);
#pragma unroll
        for (int p = 0; p < BR; ++p)
            gload_lds16(Bb + (size_t)32 * p * K + k0, BsW + p * 2048);
        __syncthreads();
#pragma unroll
        for (int half = 0; half < 2; ++half) {
            const int cb = ((half * 4 + kq) ^ (ln & 7)) * 8;
            bf16x8 bfr[4];
#pragma unroll
            for (int j = 0; j < 4; ++j)
                bfr[j] = *(const bf16x8*)&Bs[(wc + j * 16 + ln) * 64 + cb];
#pragma unroll
            for (int i = 0; i < MI; ++i) {
                const bf16x8 af = *(const bf16x8*)&As[(wr + i * 16 + ln) * 64 + cb];
#pragma unroll
                for (int j = 0; j < 4; ++j)
                    acc[i][j] = __builtin_amdgcn_mfma_f32_16x16x32_bf16(af, bfr[j], acc[i][j], 0, 0, 0);
            }
        }
    }

#pragma unroll
    for (int i = 0; i < MI; ++i) {
        const int rowb = bm + wr + i * 16 + kq * 4;
#pragma unroll
        for (int j = 0; j < 4; ++j) {
            const int colg = bn + wc + j * 16 + ln;
            const float bv = (colg < split) ? bias1[colg] : bias2[colg - split];
            if (vtmode) {
                // transposed write: Vt[(b*512+colg)*1024 + key], key=rowb&1023
                union { u16x4 v; ushort u[4]; } pk;
#pragma unroll
                for (int rr = 0; rr < 4; ++rr) {
                    float v = acc[i][j][rr] + bv;
                    bf16 t = __float2bfloat16(v);
                    pk.u[rr] = *(ushort*)&t;
                }
                *(u16x4*)((ushort*)Cv + ((size_t)(rowb >> 10) * 512 + colg) * 1024 + (rowb & 1023)) = pk.v;
            } else {
#pragma unroll
                for (int rr = 0; rr < 4; ++rr) {
                    float v = acc[i][j][rr] + bv;
                    if (relu) v = fmaxf(v, 0.f);
                    if (OUTBF16)
                        ((bf16*)Cv)[(size_t)(rowb + rr) * N + colg] = __float2bfloat16(v);
                    else
                        ((float*)Cv)[(size_t)(rowb + rr) * N + colg] = v;
                }
            }
        }
    }
}

// ---------------------------------------------------------------- MFMA flash attention
// One block per (qt, b*8+h). 4 waves x 16 q-rows, j-tiles of 64 keys.
// QK: [t][1024] (Q cols h*64, K cols 512+h*64); Vt: [(b*8+h)*64+d][1024 keys].
// XCD swizzle: bh%8 -> XCD so each XCD's K/V working set (8 heads x 256KB) fits L2.
__global__ __launch_bounds__(256) void attn_kernel(
    const bf16* __restrict__ QK, const bf16* __restrict__ Vt,
    bf16* __restrict__ Og)
{
    __shared__ ushort Qs[64 * 68];
    __shared__ ushort Ks[64 * 68];
    __shared__ ushort Vs[64 * 68];      // [dim][key] for current j-tile
    __shared__ ushort Ps[4 * 16 * 68];  // per-wave P (16 q-rows x 64 keys)

    const int tid = threadIdx.x;
    const int wave = tid >> 6, lane = tid & 63;
    const int ln = lane & 15, kq = lane >> 4;
    const int lin = blockIdx.x + 16 * blockIdx.y;
    const int loc = lin >> 3;
    const int qt = loc & 15;
    const int bh = (lin & 7) + 8 * (loc >> 4);
    const int b = bh >> 3, h = bh & 7;

    const int srow = tid >> 2;
    const int sc0 = (tid & 3) * 16;
    {
        const bf16* src = QK + (size_t)(b * SEQ + qt * 64 + srow) * 1024 + h * 64 + sc0;
        *(bf16x8*)&Qs[srow * 68 + sc0] = *(const bf16x8*)src;
        *(bf16x8*)&Qs[srow * 68 + sc0 + 8] = *(const bf16x8*)(src + 8);
    }

    float m2[4], lsum[4];
    f32x4 oacc[4];
#pragma unroll
    for (int r = 0; r < 4; ++r) { m2[r] = -INFINITY; lsum[r] = 0.f; oacc[r] = (f32x4){0.f,0.f,0.f,0.f}; }
    const float sc2 = 0.125f * 1.4426950408889634f;   // 1/sqrt(64) * log2(e)

    for (int kt = 0; kt <= qt; ++kt) {
        __syncthreads();   // prev-iter LDS reads (and initial Q write) complete
        {
            const bf16* ksrc = QK + (size_t)(b * SEQ + kt * 64 + srow) * 1024 + 512 + h * 64 + sc0;
            *(bf16x8*)&Ks[srow * 68 + sc0] = *(const bf16x8*)ksrc;
            *(bf16x8*)&Ks[srow * 68 + sc0 + 8] = *(const bf16x8*)(ksrc + 8);
            const bf16* vsrc = Vt + (size_t)(bh * 64 + srow) * SEQ + kt * 64 + sc0;
            *(bf16x8*)&Vs[srow * 68 + sc0] = *(const bf16x8*)vsrc;
            *(bf16x8*)&Vs[srow * 68 + sc0 + 8] = *(const bf16x8*)(vsrc + 8);
        }
        __syncthreads();

        // S = Q K^T : per wave 16x64, 4 col-tiles x 2 k-halves
        const bf16x8 aq0 = *(const bf16x8*)&Qs[(wave * 16 + ln) * 68 + kq * 8];
        const bf16x8 aq1 = *(const bf16x8*)&Qs[(wave * 16 + ln) * 68 + 32 + kq * 8];
        f32x4 s[4];
#pragma unroll
        for (int c = 0; c < 4; ++c) {
            const bf16x8 bk0 = *(const bf16x8*)&Ks[(c * 16 + ln) * 68 + kq * 8];
            const bf16x8 bk1 = *(const bf16x8*)&Ks[(c * 16 + ln) * 68 + 32 + kq * 8];
            s[c] = (f32x4){0.f, 0.f, 0.f, 0.f};
            s[c] = __builtin_amdgcn_mfma_f32_16x16x32_bf16(aq0, bk0, s[c], 0, 0, 0);
            s[c] = __builtin_amdgcn_mfma_f32_16x16x32_bf16(aq1, bk1, s[c], 0, 0, 0);
        }
        // scale into log2 domain (+ causal mask on the diagonal tile)
        if (kt == qt) {
#pragma unroll
            for (int c = 0; c < 4; ++c)
#pragma unroll
                for (int r = 0; r < 4; ++r) {
                    const int qg = wave * 16 + kq * 4 + r;
                    const int jg = c * 16 + ln;
                    s[c][r] = (jg <= qg) ? s[c][r] * sc2 : -INFINITY;
                }
        } else {
#pragma unroll
            for (int c = 0; c < 4; ++c)
#pragma unroll
                for (int r = 0; r < 4; ++r) s[c][r] *= sc2;
        }
        // online softmax: row reductions via shfl_xor over the 16-lane col group
        float alpha[4];
#pragma unroll
        for (int r = 0; r < 4; ++r) {
            float v = fmaxf(fmaxf(s[0][r], s[1][r]), fmaxf(s[2][r], s[3][r]));
            v = fmaxf(v, __shfl_xor(v, 1));
            v = fmaxf(v, __shfl_xor(v, 2));
            v = fmaxf(v, __shfl_xor(v, 4));
            v = fmaxf(v, __shfl_xor(v, 8));
            const float mn = fmaxf(m2[r], v);
            alpha[r] = exp2f(m2[r] - mn);
            m2[r] = mn;
        }
        float rs[4] = {0.f, 0.f, 0.f, 0.f};
#pragma unroll
        for (int c = 0; c < 4; ++c)
#pragma unroll
            for (int r = 0; r < 4; ++r) {
                const float pv = exp2f(s[c][r] - m2[r]);
                rs[r] += pv;
                // C-layout -> LDS (wave-private region, stride-68: conflict-free)
                *(bf16*)&Ps[wave * 1088 + (kq * 4 + r) * 68 + c * 16 + ln] = __float2bfloat16(pv);
            }
#pragma unroll
        for (int r = 0; r < 4; ++r) {
            float v = rs[r];
            v += __shfl_xor(v, 1);
            v += __shfl_xor(v, 2);
            v += __shfl_xor(v, 4);
            v += __shfl_xor(v, 8);
            lsum[r] = lsum[r] * alpha[r] + v;
        }
#pragma unroll
        for (int c2 = 0; c2 < 4; ++c2)
#pragma unroll
            for (int r = 0; r < 4; ++r) oacc[c2][r] *= alpha[r];
        // P V : P back from LDS in A-layout (same-wave RAW, lgkmcnt handled by compiler)
        const bf16x8 ap0 = *(const bf16x8*)&Ps[wave * 1088 + ln * 68 + kq * 8];
        const bf16x8 ap1 = *(const bf16x8*)&Ps[wave * 1088 + ln * 68 + 32 + kq * 8];
#pragma unroll
        for (int c2 = 0; c2 < 4; ++c2) {
            const bf16x8 bv0 = *(const bf16x8*)&Vs[(c2 * 16 + ln) * 68 + kq * 8];
            const bf16x8 bv1 = *(const bf16x8*)&Vs[(c2 * 16 + ln) * 68 + 32 + kq * 8];
            oacc[c2] = __builtin_amdgcn_mfma_f32_16x16x32_bf16(ap0, bv0, oacc[c2], 0, 0, 0);
            oacc[c2] = __builtin_amdgcn_mfma_f32_16x16x32_bf16(ap1, bv1, oacc[c2], 0, 0, 0);
        }
    }
    float inv[4];
#pragma unroll
    for (int r = 0; r < 4; ++r) inv[r] = 1.f / lsum[r];
#pragma unroll
    for (int c2 = 0; c2 < 4; ++c2)
#pragma unroll
        for (int r = 0; r < 4; ++r)
            Og[(size_t)(b * SEQ + qt * 64 + wave * 16 + kq * 4 + r) * 512 + h * 64 + c2 * 16 + ln]
                = __float2bfloat16(oacc[c2][r] * inv[r]);
}

// ---------------------------------------------------------------- layernorm pair
// out = LN(x + res) * s + b ; blockIdx.y picks problem 0/1.
__global__ __launch_bounds__(256) void lnp_kernel(
    const float* __restrict__ x0, const bf16* __restrict__ r0, const float* __restrict__ s0,
    const float* __restrict__ b0, float* __restrict__ of0, bf16* __restrict__ oh0,
    const float* __restrict__ x1, const bf16* __restrict__ r1, const float* __restrict__ s1,
    const float* __restrict__ b1, float* __restrict__ of1, bf16* __restrict__ oh1)
{
    const float* x = x0; const bf16* res = r0; const float* s = s0; const float* bb = b0;
    float* of = of0; bf16* oh = oh0;
    if (blockIdx.y) { x = x1; res = r1; s = s1; bb = b1; of = of1; oh = oh1; }
    __shared__ float w1[4], w2[4];
    const size_t o = (size_t)blockIdx.x * DM;
    const int i0 = threadIdx.x, i1 = threadIdx.x + 256;
    const float v0 = x[o + i0] + __bfloat162float(res[o + i0]);
    const float v1 = x[o + i1] + __bfloat162float(res[o + i1]);
    float sum = v0 + v1;
#pragma unroll
    for (int off = 32; off; off >>= 1) sum += __shfl_down(sum, off);
    if ((threadIdx.x & 63) == 0) w1[threadIdx.x >> 6] = sum;
    __syncthreads();
    const float mu = (w1[0] + w1[1] + w1[2] + w1[3]) * (1.f / DM);
    const float d0 = v0 - mu, d1 = v1 - mu;
    float vs = d0 * d0 + d1 * d1;
#pragma unroll
    for (int off = 32; off; off >>= 1) vs += __shfl_down(vs, off);
    if ((threadIdx.x & 63) == 0) w2[threadIdx.x >> 6] = vs;
    __syncthreads();
    const float rstd = rsqrtf((w2[0] + w2[1] + w2[2] + w2[3]) * (1.f / DM) + 1e-5f);
    const float o0 = d0 * rstd * s[i0] + bb[i0];
    const float o1 = d1 * rstd * s[i1] + bb[i1];
    of[o + i0] = o0; of[o + i1] = o1;
    oh[o + i0] = __float2bfloat16(o0);
    oh[o + i1] = __float2bfloat16(o1);
}

// ---------------------------------------------------------------- head gather
__global__ __launch_bounds__(256) void gather_kernel(
    const bf16* __restrict__ ctx16, const bf16* __restrict__ val16,
    const float* __restrict__ skill, const int* __restrict__ q,
    bf16* __restrict__ feat)
{
    const int t = blockIdx.x;
    const float* sp = skill + (size_t)q[t] * DM;
    const bf16* cp = ctx16 + (size_t)t * DM;
    const bf16* vp = val16 + (size_t)t * DM;
    bf16* fp = feat + (size_t)t * (3 * DM);
    for (int d = threadIdx.x; d < DM; d += 256) {
        fp[d] = cp[d];
        fp[DM + d] = vp[d];
        fp[2 * DM + d] = __float2bfloat16(sp[d]);
    }
}

// ---------------------------------------------------------------- logits
__global__ __launch_bounds__(256) void logits_kernel(
    const float* __restrict__ h2, const float* __restrict__ w,
    const float* __restrict__ bptr, float* __restrict__ out)
{
    __shared__ float w1[4];
    const int t = blockIdx.x;
    float sum = h2[(size_t)t * 256 + threadIdx.x] * w[threadIdx.x];
#pragma unroll
    for (int off = 32; off; off >>= 1) sum += __shfl_down(sum, off);
    if ((threadIdx.x & 63) == 0) w1[threadIdx.x >> 6] = sum;
    __syncthreads();
    if (threadIdx.x == 0) {
        const float logit = w1[0] + w1[1] + w1[2] + w1[3] + bptr[0];
        out[t] = 1.f / (1.f + __expf(-logit));
    }
}

// ---------------------------------------------------------------- launch
extern "C" void kernel_launch(void* const* d_in, const int* in_sizes, int n_in,
                              void* d_out, int out_size, void* d_ws, size_t ws_size,
                              hipStream_t stream)
{
    const int*   q         = (const int*)d_in[0];
    const int*   r         = (const int*)d_in[1];
    const float* ctx_emb   = (const float*)d_in[2];
    const float* val_emb   = (const float*)d_in[3];
    const float* skill_emb = (const float*)d_in[4];
    const float* pos_emb   = (const float*)d_in[5];
    const float* Wq = (const float*)d_in[6];
    const float* bq = (const float*)d_in[7];
    const float* Wk = (const float*)d_in[8];
    const float* bk = (const float*)d_in[9];
    const float* Wv = (const float*)d_in[10];
    const float* bv = (const float*)d_in[11];
    const float* Wo = (const float*)d_in[12];
    const float* bo = (const float*)d_in[13];
    const float* ln1c_s = (const float*)d_in[14];
    const float* ln1c_b = (const float*)d_in[15];
    const float* ln1v_s = (const float*)d_in[16];
    const float* ln1v_b = (const float*)d_in[17];
    const float* ln2c_s = (const float*)d_in[18];
    const float* ln2c_b = (const float*)d_in[19];
    const float* ln2v_s = (const float*)d_in[20];
    const float* ln2v_b = (const float*)d_in[21];
    const float* fc1c_W = (const float*)d_in[22];
    const float* fc1c_b = (const float*)d_in[23];
    const float* fc2c_W = (const float*)d_in[24];
    const float* fc2c_b = (const float*)d_in[25];
    const float* fc1v_W = (const float*)d_in[26];
    const float* fc1v_b = (const float*)d_in[27];
    const float* fc2v_W = (const float*)d_in[28];
    const float* fc2v_b = (const float*)d_in[29];
    const float* hW1 = (const float*)d_in[30];
    const float* hb1 = (const float*)d_in[31];
    const float* hW2 = (const float*)d_in[32];
    const float* hb2 = (const float*)d_in[33];
    const float* hW3 = (const float*)d_in[34];
    const float* hb3 = (const float*)d_in[35];
    float* out = (float*)d_out;

    char* p = (char*)d_ws;
    auto alloc = [&](size_t bytes) { char* ret = p; p += bytes; return ret; };
    float* ctx32 = (float*)alloc(16777216);
    float* val32 = (float*)alloc(16777216);
    bf16*  ob16c = (bf16*)alloc(8388608);
    bf16*  ob16v = (bf16*)alloc(8388608);
    bf16*  ctx16 = (bf16*)alloc(8388608);
    bf16*  val16 = (bf16*)alloc(8388608);
    bf16*  qk16  = (bf16*)alloc(16777216);   // A: [8192][1024]
    bf16*  v16pad= (bf16*)alloc(8388608);    // B: dead (kept for alias sizing)
    bf16*  vt16  = (bf16*)alloc(8388608);    // C: [(b*8+h)*64+d][1024]
    bf16*  att16 = (bf16*)alloc(8388608);    // D
    bf16*  mid16c = (bf16*)alloc(33554432);  // [8192][2048]
    bf16*  qkT   = (bf16*)alloc(4194304);    // [4][1024][512]
    bf16*  vT    = (bf16*)alloc(2097152);    // [4][512][512]
    bf16*  oT    = (bf16*)alloc(2097152);
    bf16*  fc1cT = (bf16*)alloc(8388608);    // [4][2048][512]
    bf16*  fc2cT = (bf16*)alloc(8388608);    // [4][512][2048]
    bf16*  fc1vT = (bf16*)alloc(8388608);
    bf16*  fc2vT = (bf16*)alloc(8388608);
    bf16*  hW1T  = (bf16*)alloc(6291456);    // [2048][1536]
    bf16*  hW2T  = (bf16*)alloc(1048576);    // [256][2048]
    (void)v16pad;
    // aliases (liveness-checked):
    bf16*  mid16v = qk16;                    // A+B+C = exactly 33.5 MB, dead during FFN
    bf16*  feat16 = qk16;                    // A+B = exactly 8192*1536*2, post-loop
    float* h2     = (float*)vt16;            // C = exactly 8192*256*4, post-loop

    const dim3 tb(32, 8);
    transpose_kernel<<<dim3(16, 16, 4), tb, 0, stream>>>(Wq, qkT,          512, 512, 262144, 524288);
    transpose_kernel<<<dim3(16, 16, 4), tb, 0, stream>>>(Wk, qkT + 262144, 512, 512, 262144, 524288);
    transpose_kernel<<<dim3(16, 16, 4), tb, 0, stream>>>(Wv, vT, 512, 512, 262144, 262144);
    transpose_kernel<<<dim3(16, 16, 4), tb, 0, stream>>>(Wo, oT, 512, 512, 262144, 262144);
    transpose_kernel<<<dim3(64, 16, 4), tb, 0, stream>>>(fc1c_W, fc1cT, 512, 2048, 1048576, 1048576);
    transpose_kernel<<<dim3(16, 64, 4), tb, 0, stream>>>(fc2c_W, fc2cT, 2048, 512, 1048576, 1048576);
    transpose_kernel<<<dim3(64, 16, 4), tb, 0, stream>>>(fc1v_W, fc1vT, 512, 2048, 1048576, 1048576);
    transpose_kernel<<<dim3(16, 64, 4), tb, 0, stream>>>(fc2v_W, fc2vT, 2048, 512, 1048576, 1048576);
    transpose_kernel<<<dim3(64, 48, 1), tb, 0, stream>>>(hW1, hW1T, 1536, 2048, 0, 0);
    transpose_kernel<<<dim3(8, 64, 1),  tb, 0, stream>>>(hW2, hW2T, 2048, 256, 0, 0);

    embed_kernel<<<TOK, 256, 0, stream>>>(q, r, ctx_emb, val_emb, pos_emb,
                                          ctx32, val32, ctx16, val16);

    for (int i = 0; i < NBLK; ++i) {
        mfma_gemm<128, true><<<dim3(8, 64), 256, 0, stream>>>(
            (const ushort*)ctx16, (const ushort*)(qkT + (size_t)i * 524288),
            bq + i * DM, bk + i * DM, 512, qk16, 1024, 512, 0, 0,
            nullptr, nullptr, nullptr, nullptr);
        mfma_gemm<64, true><<<dim3(8, 64), 256, 0, stream>>>(
            (const ushort*)val16, (const ushort*)(vT + (size_t)i * 262144),
            bv + i * DM, nullptr, 1 << 30, vt16, 512, 512, 0, 1,
            nullptr, nullptr, nullptr, nullptr);
        attn_kernel<<<dim3(16, 64), 256, 0, stream>>>(qk16, vt16, att16);
        mfma_gemm<64, true><<<dim3(8, 64), 256, 0, stream>>>(
            (const ushort*)att16, (const ushort*)(oT + (size_t)i * 262144),
            bo + i * DM, nullptr, 1 << 30, ob16c, 512, 512, 0, 0,
            nullptr, nullptr, nullptr, nullptr);
        lnp_kernel<<<dim3(TOK, 2), 256, 0, stream>>>(
            ctx32, ob16c, ln1c_s + i * DM, ln1c_b + i * DM, ctx32, ctx16,
            val32, ob16c, ln1v_s + i * DM, ln1v_b + i * DM, val32, val16);
        mfma_gemm<128, true><<<dim3(16, 64, 2), 256, 0, stream>>>(
            (const ushort*)ctx16, (const ushort*)(fc1cT + (size_t)i * 1048576),
            fc1c_b + i * DFFN, nullptr, 1 << 30, mid16c, 2048, 512, 1, 0,
            (const ushort*)val16, (const ushort*)(fc1vT + (size_t)i * 1048576),
            fc1v_b + i * DFFN, mid16v);
        mfma_gemm<128, true><<<dim3(4, 64, 2), 256, 0, stream>>>(
            (const ushort*)mid16c, (const ushort*)(fc2cT + (size_t)i * 1048576),
            fc2c_b + i * DM, nullptr, 1 << 30, ob16c, 512, 2048, 0, 0,
            (const ushort*)mid16v, (const ushort*)(fc2vT + (size_t)i * 1048576),
            fc2v_b + i * DM, ob16v);
        lnp_kernel<<<dim3(TOK, 2), 256, 0, stream>>>(
            ctx32, ob16c, ln2c_s + i * DM, ln2c_b + i * DM, ctx32, ctx16,
            val32, ob16v, ln2v_s + i * DM, ln2v_b + i * DM, val32, val16);
    }

    gather_kernel<<<TOK, 256, 0, stream>>>(ctx16, val16, skill_emb, q, feat16);
    mfma_gemm<128, true><<<dim3(16, 64), 256, 0, stream>>>(
        (const ushort*)feat16, (const ushort*)hW1T, hb1, nullptr, 1 << 30, mid16c, 2048, 1536, 1, 0,
        nullptr, nullptr, nullptr, nullptr);
    mfma_gemm<64, false><<<dim3(4, 64), 256, 0, stream>>>(
        (const ushort*)mid16c, (const ushort*)hW2T, hb2, nullptr, 1 << 30, h2, 256, 2048, 1, 0,
        nullptr, nullptr, nullptr, nullptr);
    logits_kernel<<<TOK, 256, 0, stream>>>(h2, hW3, hb3, out);
}